// Round 9
// baseline (386.602 us; speedup 1.0000x reference)
//
#include <hip/hip_runtime.h>
#include <hip/hip_bf16.h>
#include <math.h>

// Problem dims (fixed by reference)
#define BB   256      // batch
#define LDE  64       // desc tokens len
#define NO   10240    // outer nodes
#define LO   32       // x tokens len
#define NM   81920    // mini nodes
#define LM   16       // mini tokens len
#define EO   81920    // outer edges
#define EM   327680   // mini edges
#define ED   128      // embed dim E
#define HIDD 256      // hidden
#define NH   8        // heads
#define DH   16       // head dim
#define VV   10000    // vocab

static inline int nblk(long long n, int b) { return (int)((n + b - 1) / b); }

typedef __attribute__((ext_vector_type(8))) short short8;
typedef __attribute__((ext_vector_type(4))) float f32x4;

// ---- fp32 <-> bf16 (RNE) helpers ----
static __device__ __forceinline__ unsigned short bf16_rne(float f) {
  unsigned u = __float_as_uint(f);
  return (unsigned short)((u + 0x7fffu + ((u >> 16) & 1u)) >> 16);
}
static __device__ __forceinline__ float bf16_to_f(unsigned short h) {
  return __uint_as_float(((unsigned)h) << 16);
}
static __device__ __forceinline__ float4 b4f(ushort4 h) {
  return make_float4(bf16_to_f(h.x), bf16_to_f(h.y), bf16_to_f(h.z), bf16_to_f(h.w));
}

// ============ merged conversion kernel: 6 weights -> split-bf16 frags, 2 tables -> bf16
struct WC { const float* W; int K, M; short8* hi; short8* lo; int base; };
struct WC6 { WC w[6]; };
__global__ void __launch_bounds__(256)
conv_all_k(WC6 wc, const float* __restrict__ t1, unsigned short* __restrict__ o1,
           const float* __restrict__ t2, unsigned short* __restrict__ o2) {
  if (blockIdx.x < 64) {
    int g = blockIdx.x * 256 + threadIdx.x;   // octet id, 0..16383
    int wi = 0;
    #pragma unroll
    for (int i = 1; i < 6; ++i) if (g >= wc.w[i].base) wi = i;
    const WC c = wc.w[wi];
    int idx = g - c.base;
    int lane = idx & 63;
    int nt = (idx >> 6) % (c.M / 16);
    int kb = (idx >> 6) / (c.M / 16);
    int n = nt * 16 + (lane & 15);
    int k0 = kb * 32 + ((lane >> 4) << 3);
    short8 h, l;
    #pragma unroll
    for (int j = 0; j < 8; ++j) {
      float v = c.W[(size_t)(k0 + j) * c.M + n];
      unsigned short hb = bf16_rne(v);
      h[j] = (short)hb;
      l[j] = (short)bf16_rne(v - bf16_to_f(hb));
    }
    c.hi[idx] = h; c.lo[idx] = l;
  } else {
    int q = (blockIdx.x - 64) * 256 + threadIdx.x;   // quad id
    const int NT = VV * ED / 4;                       // 320000 per table
    if (q < NT) {
      float4 v = *(const float4*)(t1 + (size_t)q * 4);
      *(ushort4*)(o1 + (size_t)q * 4) =
          make_ushort4(bf16_rne(v.x), bf16_rne(v.y), bf16_rne(v.z), bf16_rne(v.w));
    } else if (q < 2 * NT) {
      int q2 = q - NT;
      float4 v = *(const float4*)(t2 + (size_t)q2 * 4);
      *(ushort4*)(o2 + (size_t)q2 * 4) =
          make_ushort4(bf16_rne(v.x), bf16_rne(v.y), bf16_rne(v.z), bf16_rne(v.w));
    }
  }
}

// ---- embedding masked mean body: 256 thr = 8 rows x 32 4-elem lanes ----
template<int L, bool TBF, bool OUTBF>
static __device__ __forceinline__ void embed_body(const int* __restrict__ tokens,
                                                  const void* __restrict__ table,
                                                  void* __restrict__ out, int blk) {
  const int r = threadIdx.x >> 5, lane = threadIdx.x & 31;
  const int n0 = blk * 8;
  __shared__ int toks[8][L];
  for (int i = threadIdx.x; i < 8 * L; i += 256)
    toks[i / L][i % L] = tokens[(size_t)n0 * L + i];
  __syncthreads();
  float4 acc = make_float4(0.f, 0.f, 0.f, 0.f);
  int cnt = 0;
  #pragma unroll
  for (int l = 0; l < L; ++l) {
    int t = toks[r][l];
    float4 v;
    if (TBF) v = b4f(*((const ushort4*)((const unsigned short*)table + (size_t)t * ED + lane * 4)));
    else     v = *(const float4*)((const float*)table + (size_t)t * ED + lane * 4);
    float msk = (t != 0) ? 1.f : 0.f;
    cnt += (t != 0);
    acc.x = fmaf(msk, v.x, acc.x); acc.y = fmaf(msk, v.y, acc.y);
    acc.z = fmaf(msk, v.z, acc.z); acc.w = fmaf(msk, v.w, acc.w);
  }
  float inv = 1.f / (float)(cnt > 0 ? cnt : 1);
  acc.x *= inv; acc.y *= inv; acc.z *= inv; acc.w *= inv;
  if (OUTBF)
    *(ushort4*)((unsigned short*)out + (size_t)(n0 + r) * ED + lane * 4) =
        make_ushort4(bf16_rne(acc.x), bf16_rne(acc.y), bf16_rne(acc.z), bf16_rne(acc.w));
  else
    *(float4*)((float*)out + (size_t)(n0 + r) * ED + lane * 4) = acc;
}

// all three embeddings in one launch: [0,32) desc | [32,1312) x | [1312,11552) mini
__global__ void __launch_bounds__(256)
embed_all_k(const int* __restrict__ desc_tokens, const float* __restrict__ desc_table,
            float* __restrict__ h_n,
            const int* __restrict__ x_tokens, const unsigned short* __restrict__ ctab2,
            float* __restrict__ stmt,
            const int* __restrict__ mini_tokens, const unsigned short* __restrict__ ctab,
            unsigned short* __restrict__ miniE) {
  int b = blockIdx.x;
  if (b < BB / 8) embed_body<LDE, false, false>(desc_tokens, desc_table, h_n, b);
  else if (b < BB / 8 + NO / 8) embed_body<LO, true, false>(x_tokens, ctab2, stmt, b - BB / 8);
  else embed_body<LM, true, true>(mini_tokens, ctab, miniE, b - BB / 8 - NO / 8);
}

// ========== QKVS GEMM v4: zero LDS, A-fragments loaded straight from global ==========
// A (bf16, row-major) is MFMA-A-fragment compatible: lane reads 16B at
// A[n0 + mtile*16 + (lane&15)][kb*32 + (lane>>4)*8] — 16 full cache lines per instr.
struct QDesc { const short8* bh; const short8* bl; const float* bias; unsigned short* C; };
struct QDesc4 { QDesc d[4]; };

__global__ void __launch_bounds__(256)
mgemm_qkvs4_k(const unsigned short* __restrict__ Ab, QDesc4 g4) {
  const QDesc d = g4.d[blockIdx.x];
  const int n0 = blockIdx.y * 128;
  const int tid = threadIdx.x;
  const int w = tid >> 6, lane = tid & 63;
  const int wm = (w & 1) * 4, wn = (w >> 1) * 4;
  const int r = lane & 15, qd = lane >> 4;
  f32x4 acc[4][4];
  #pragma unroll
  for (int i = 0; i < 4; ++i)
    #pragma unroll
    for (int j = 0; j < 4; ++j) acc[i][j] = (f32x4){0.f, 0.f, 0.f, 0.f};
  #pragma unroll
  for (int kb = 0; kb < 4; ++kb) {
    short8 bh[4], bl[4];
    #pragma unroll
    for (int j = 0; j < 4; ++j) {
      size_t bi = ((size_t)kb * 8 + wn + j) * 64 + lane;
      bh[j] = d.bh[bi]; bl[j] = d.bl[bi];
    }
    short8 a[4];
    #pragma unroll
    for (int i = 0; i < 4; ++i)
      a[i] = *(const short8*)(Ab + (size_t)(n0 + (wm + i) * 16 + r) * ED + kb * 32 + qd * 8);
    #pragma unroll
    for (int i = 0; i < 4; ++i)
      #pragma unroll
      for (int j = 0; j < 4; ++j) {
        acc[i][j] = __builtin_amdgcn_mfma_f32_16x16x32_bf16(a[i], bh[j], acc[i][j], 0, 0, 0);
        acc[i][j] = __builtin_amdgcn_mfma_f32_16x16x32_bf16(a[i], bl[j], acc[i][j], 0, 0, 0);
      }
  }
  #pragma unroll
  for (int i = 0; i < 4; ++i)
    #pragma unroll
    for (int j = 0; j < 4; ++j) {
      int col = (wn + j) * 16 + r;
      float bv = d.bias[col];
      #pragma unroll
      for (int rr = 0; rr < 4; ++rr) {
        int row = (wm + i) * 16 + qd * 4 + rr;
        d.C[(size_t)(n0 + row) * ED + col] = bf16_rne(acc[i][j][rr] + bv);
      }
    }
}

// ================= MFMA GEMM (fp32 A, split-bf16 3-term): W2 / W3 path ==============
template<bool RELU>
__global__ void __launch_bounds__(256)
mgemm_k(const float* __restrict__ A, const short8* __restrict__ Bh,
        const short8* __restrict__ Bl, const float* __restrict__ bias,
        float* C, int K, int M) {
  __shared__ short8 Ah[8][64];
  __shared__ short8 Al[8][64];
  const int bm0 = blockIdx.y * 128, bn0 = blockIdx.x * 128;
  const int tid = threadIdx.x;
  const int w = tid >> 6, lane = tid & 63;
  const int wm = (w & 1) * 4, wn = (w >> 1) * 4;
  const int NTm = M / 16;
  f32x4 acc[4][4];
  #pragma unroll
  for (int i = 0; i < 4; ++i)
    #pragma unroll
    for (int j = 0; j < 4; ++j) acc[i][j] = (f32x4){0.f, 0.f, 0.f, 0.f};
  const int kbn = K / 32;
  for (int kb = 0; kb < kbn; ++kb) {
    __syncthreads();
    #pragma unroll
    for (int it = 0; it < 2; ++it) {
      int u = tid + it * 256;
      int mt = u >> 6, l = u & 63;
      int m = bm0 + mt * 16 + (l & 15);
      int k = kb * 32 + ((l >> 4) << 3);
      const float* ap = A + (size_t)m * K + k;
      float4 v0 = *(const float4*)ap;
      float4 v1 = *(const float4*)(ap + 4);
      float f[8] = {v0.x, v0.y, v0.z, v0.w, v1.x, v1.y, v1.z, v1.w};
      short8 hh, ll;
      #pragma unroll
      for (int j = 0; j < 8; ++j) {
        unsigned short hb = bf16_rne(f[j]);
        hh[j] = (short)hb;
        ll[j] = (short)bf16_rne(f[j] - bf16_to_f(hb));
      }
      Ah[mt][l] = hh; Al[mt][l] = ll;
    }
    __syncthreads();
    short8 bh[4], bl[4];
    #pragma unroll
    for (int j = 0; j < 4; ++j) {
      size_t bi = ((size_t)kb * NTm + (bn0 >> 4) + wn + j) * 64 + lane;
      bh[j] = Bh[bi]; bl[j] = Bl[bi];
    }
    #pragma unroll
    for (int i = 0; i < 4; ++i) {
      short8 ah = Ah[wm + i][lane];
      short8 al = Al[wm + i][lane];
      #pragma unroll
      for (int j = 0; j < 4; ++j) {
        acc[i][j] = __builtin_amdgcn_mfma_f32_16x16x32_bf16(ah, bh[j], acc[i][j], 0, 0, 0);
        acc[i][j] = __builtin_amdgcn_mfma_f32_16x16x32_bf16(ah, bl[j], acc[i][j], 0, 0, 0);
        acc[i][j] = __builtin_amdgcn_mfma_f32_16x16x32_bf16(al, bh[j], acc[i][j], 0, 0, 0);
      }
    }
  }
  const int q = lane >> 4, c = lane & 15;
  #pragma unroll
  for (int i = 0; i < 4; ++i)
    #pragma unroll
    for (int j = 0; j < 4; ++j) {
      int col = bn0 + (wn + j) * 16 + c;
      float bv = bias ? bias[col] : 0.f;
      #pragma unroll
      for (int rr = 0; rr < 4; ++rr) {
        int row = bm0 + (wm + i) * 16 + q * 4 + rr;
        float v = acc[i][j][rr] + bv;
        if (RELU) v = fmaxf(v, 0.f);
        C[(size_t)row * M + col] = v;
      }
    }
}

// ================= CSR build =================
__global__ void hist2_k(const int* __restrict__ dm, int* __restrict__ hm,
                        const int* __restrict__ dd, int* __restrict__ ho) {
  int e = blockIdx.x * 256 + threadIdx.x;
  if (e < EM) atomicAdd(&hm[dm[e]], 1);
  else { int e2 = e - EM; if (e2 < EO) atomicAdd(&ho[dd[e2]], 1); }
}
__global__ void chunk_sum_k(const int* __restrict__ hist, int* __restrict__ partials, int N) {
  __shared__ int sd[256];
  int i = blockIdx.x * 256 + threadIdx.x;
  sd[threadIdx.x] = (i < N) ? hist[i] : 0;
  __syncthreads();
  for (int s = 128; s > 0; s >>= 1) {
    if (threadIdx.x < s) sd[threadIdx.x] += sd[threadIdx.x + s];
    __syncthreads();
  }
  if (threadIdx.x == 0) partials[blockIdx.x] = sd[0];
}
__global__ void scan_partials_k(int* __restrict__ p, int B) {  // one block, 512 thr
  __shared__ int sd[512];
  int t = threadIdx.x;
  int v = (t < B) ? p[t] : 0;
  sd[t] = v; __syncthreads();
  for (int off = 1; off < 512; off <<= 1) {
    int a = (t >= off) ? sd[t - off] : 0;
    __syncthreads();
    sd[t] += a;
    __syncthreads();
  }
  if (t < B) p[t] = sd[t] - v;   // exclusive
}
__global__ void scan_final_k(const int* __restrict__ hist, const int* __restrict__ partials,
                             int* __restrict__ offs, int* __restrict__ cursor, int N,
                             float* __restrict__ dinv) {
  __shared__ int sd[256];
  int i = blockIdx.x * 256 + threadIdx.x;
  int v = (i < N) ? hist[i] : 0;
  sd[threadIdx.x] = v; __syncthreads();
  for (int off = 1; off < 256; off <<= 1) {
    int a = (threadIdx.x >= off) ? sd[threadIdx.x - off] : 0;
    __syncthreads();
    sd[threadIdx.x] += a;
    __syncthreads();
  }
  if (i < N) {
    int excl = sd[threadIdx.x] - v + partials[blockIdx.x];
    offs[i] = excl;
    cursor[i] = excl;
    if (i == N - 1) offs[N] = excl + v;
    if (dinv) dinv[i] = 1.f / sqrtf(1.f + (float)v);
  }
}
__global__ void scatter2_k(const int* __restrict__ sm, const int* __restrict__ dm,
                           int* __restrict__ cm, int* __restrict__ km,
                           const int* __restrict__ so, const int* __restrict__ dd,
                           int* __restrict__ co, int* __restrict__ ko) {
  int e = blockIdx.x * 256 + threadIdx.x;
  if (e < EM) {
    int pos = atomicAdd(&cm[dm[e]], 1);
    km[pos] = sm[e];
  } else {
    int e2 = e - EM;
    if (e2 < EO) {
      int pos = atomicAdd(&co[dd[e2]], 1);
      ko[pos] = so[e2];
    }
  }
}

// ============ fused TransformerConv (bf16 streams): flash per dst + skip + gate ======
__global__ void __launch_bounds__(128)
attn_fused_k(unsigned short* qh, const unsigned short* __restrict__ kk,
             const unsigned short* __restrict__ vv, const unsigned short* __restrict__ skip,
             const int* __restrict__ offs, const int* __restrict__ csr,
             const float* __restrict__ Wg, const float* __restrict__ bg,
             float* __restrict__ gateOut) {
  const int g = threadIdx.x >> 5, lane = threadIdx.x & 31;
  const int n = blockIdx.x * 4 + g;
  float4 q = b4f(*(const ushort4*)(qh + (size_t)n * ED + lane * 4));
  int lo = offs[n], hi = offs[n + 1];
  float4 O = make_float4(0.f, 0.f, 0.f, 0.f);
  float m = -INFINITY, l = 0.f;
  for (int e = lo; e < hi; ++e) {
    int s = csr[e];
    float4 kt = b4f(*(const ushort4*)(kk + (size_t)s * ED + lane * 4));
    float4 vt = b4f(*(const ushort4*)(vv + (size_t)s * ED + lane * 4));
    float p = q.x * kt.x + q.y * kt.y + q.z * kt.z + q.w * kt.w;
    p += __shfl_xor(p, 1, 64);
    p += __shfl_xor(p, 2, 64);
    float sc = p * 0.25f;               // 1/sqrt(Dh)
    float mn = fmaxf(m, sc);
    float scale = __expf(m - mn);       // exp(-inf)=0 handles first edge
    float pe = __expf(sc - mn);
    l = l * scale + pe;
    O.x = O.x * scale + pe * vt.x; O.y = O.y * scale + pe * vt.y;
    O.z = O.z * scale + pe * vt.z; O.w = O.w * scale + pe * vt.w;
    m = mn;
  }
  float inv = 1.f / (l + 1e-16f);
  float4 sk = b4f(*(const ushort4*)(skip + (size_t)n * ED + lane * 4));
  float4 out = make_float4(O.x * inv + sk.x, O.y * inv + sk.y,
                           O.z * inv + sk.z, O.w * inv + sk.w);
  *(ushort4*)(qh + (size_t)n * ED + lane * 4) =
      make_ushort4(bf16_rne(out.x), bf16_rne(out.y), bf16_rne(out.z), bf16_rne(out.w));
  float4 wg = *(const float4*)(Wg + lane * 4);
  float ps = out.x * wg.x + out.y * wg.y + out.z * wg.z + out.w * wg.w;
  #pragma unroll
  for (int o = 1; o <= 16; o <<= 1) ps += __shfl_xor(ps, o, 64);
  if (lane == 0) gateOut[n] = ps + bg[0];
}

// ============ GCN gather (fp32): 4 nodes x 32 float4-lanes ============
__global__ void __launch_bounds__(128)
gcn_gather_k(const float* __restrict__ x, const float* __restrict__ dinv,
             const int* __restrict__ offs, const int* __restrict__ csr,
             const float* __restrict__ bias, float* __restrict__ out,
             const float* __restrict__ Wg, const float* __restrict__ bg,
             float* __restrict__ gateOut) {
  const int g = threadIdx.x >> 5, lane = threadIdx.x & 31;
  const int n = blockIdx.x * 4 + g;
  float di = dinv[n];
  float4 xs = *(const float4*)(x + (size_t)n * ED + lane * 4);
  float w0 = di * di;
  float4 acc = make_float4(w0 * xs.x, w0 * xs.y, w0 * xs.z, w0 * xs.w);
  int lo = offs[n], hi = offs[n + 1];
  for (int e = lo; e < hi; ++e) {
    int s = csr[e];
    float w = di * dinv[s];
    float4 v = *(const float4*)(x + (size_t)s * ED + lane * 4);
    acc.x = fmaf(w, v.x, acc.x); acc.y = fmaf(w, v.y, acc.y);
    acc.z = fmaf(w, v.z, acc.z); acc.w = fmaf(w, v.w, acc.w);
  }
  if (bias) {
    float4 b4 = *(const float4*)(bias + lane * 4);
    acc.x += b4.x; acc.y += b4.y; acc.z += b4.z; acc.w += b4.w;
  }
  *(float4*)(out + (size_t)n * ED + lane * 4) = acc;
  if (gateOut) {
    float4 wg = *(const float4*)(Wg + lane * 4);
    float ps = acc.x * wg.x + acc.y * wg.y + acc.z * wg.z + acc.w * wg.w;
    #pragma unroll
    for (int o = 1; o <= 16; o <<= 1) ps += __shfl_xor(ps, o, 64);
    if (lane == 0) gateOut[n] = ps + bg[0];
  }
}

// ============ global attention over contiguous (sorted) segments ============
static __device__ __forceinline__ int lower_bound_d(const int* a, int n, int key) {
  int lo = 0, hi = n;
  while (lo < hi) { int mid = (lo + hi) >> 1; if (a[mid] < key) lo = mid + 1; else hi = mid; }
  return lo;
}
template<bool COMBINE, bool XBF>
__global__ void __launch_bounds__(128)
gattn_k(const void* __restrict__ xv, const float* __restrict__ gate,
        const int* __restrict__ seg, int Ntot,
        const float* __restrict__ other, float* __restrict__ out) {
  const int g = threadIdx.x >> 5, lane = threadIdx.x & 31;
  const int n = blockIdx.x * 4 + g;
  __shared__ int sh[4][2];
  if (lane == 0) {
    sh[g][0] = lower_bound_d(seg, Ntot, n);
    sh[g][1] = lower_bound_d(seg, Ntot, n + 1);
  }
  __syncthreads();
  int lo = sh[g][0], hi = sh[g][1];
  float m = -INFINITY;
  for (int j = lo; j < hi; ++j) m = fmaxf(m, gate[j]);
  float ssum = 0.f;
  for (int j = lo; j < hi; ++j) ssum += __expf(gate[j] - m);
  float inv = 1.f / (ssum + 1e-16f);
  float4 acc = make_float4(0.f, 0.f, 0.f, 0.f);
  for (int j = lo; j < hi; ++j) {
    float a = __expf(gate[j] - m) * inv;
    float4 v;
    if (XBF) v = b4f(*((const ushort4*)((const unsigned short*)xv + (size_t)j * ED + lane * 4)));
    else     v = *((const float4*)((const float*)xv + (size_t)j * ED) + lane);
    acc.x = fmaf(a, v.x, acc.x); acc.y = fmaf(a, v.y, acc.y);
    acc.z = fmaf(a, v.z, acc.z); acc.w = fmaf(a, v.w, acc.w);
  }
  if (COMBINE) {
    float4 o4 = *(const float4*)(other + (size_t)n * ED + lane * 4);
    acc.x = (acc.x + o4.x) * 0.5f; acc.y = (acc.y + o4.y) * 0.5f;
    acc.z = (acc.z + o4.z) * 0.5f; acc.w = (acc.w + o4.w) * 0.5f;
  }
  *(float4*)(out + (size_t)n * ED + lane * 4) = acc;
}

// ---- cosine similarity: one wave per batch row ----
__global__ void cosine_k(const float* __restrict__ a, const float* __restrict__ b,
                         float* __restrict__ out) {
  int n = blockIdx.x, lane = threadIdx.x;
  float x0 = a[(size_t)n * ED + lane], x1 = a[(size_t)n * ED + 64 + lane];
  float y0 = b[(size_t)n * ED + lane], y1 = b[(size_t)n * ED + 64 + lane];
  float dot = x0 * y0 + x1 * y1;
  float na = x0 * x0 + x1 * x1;
  float nb = y0 * y0 + y1 * y1;
  #pragma unroll
  for (int o = 32; o > 0; o >>= 1) {
    dot += __shfl_down(dot, o, 64);
    na  += __shfl_down(na,  o, 64);
    nb  += __shfl_down(nb,  o, 64);
  }
  if (lane == 0)
    out[n] = dot / (fmaxf(sqrtf(na), 1e-8f) * fmaxf(sqrtf(nb), 1e-8f));
}

// ---- workspace layout (4-byte element offsets) ----
constexpr size_t OFF_HN    = 0;                                  // BB*ED
constexpr size_t OFF_STMT  = OFF_HN    + (size_t)BB * ED;        // NO*ED
constexpr size_t OFF_A     = OFF_STMT  + (size_t)NO * ED;        // NM*ED (miniE bf16 -> recycled)
constexpr size_t OFF_QHID  = OFF_A     + (size_t)NM * ED;        // NM*ED floats (bf16 q->hid in 1st half)
constexpr size_t OFF_CT    = OFF_QHID  + (size_t)NM * ED / 2;    // 2nd half of QHID: bf16 tables
constexpr size_t OFF_K     = OFF_QHID  + (size_t)NM * ED;        // NM*ED floats (bf16 k + bf16 skip)
constexpr size_t OFF_V     = OFF_K     + (size_t)NM * ED;        // NM*ED floats (bf16 v in 1st half)
constexpr size_t T0        = OFF_V     + (size_t)NM * ED;
constexpr size_t OFF_GATE  = T0;                                 // NM
constexpr size_t OFF_GATE2 = OFF_GATE  + (size_t)NM;             // NO
constexpr size_t OFF_FNREP = OFF_GATE2 + (size_t)NO;             // BB*ED
constexpr size_t OFF_DINV  = OFF_FNREP + (size_t)BB * ED;        // NO
constexpr size_t OFF_HISTM = OFF_DINV  + (size_t)NO;             // NM (int)
constexpr size_t OFF_HISTO = OFF_HISTM + (size_t)NM;             // NO (adjacent -> one memset)
constexpr size_t OFF_OFFSM = OFF_HISTO + (size_t)NO;             // NM+1
constexpr size_t OFF_CURM  = OFF_OFFSM + (size_t)NM + 1;         // NM
constexpr size_t OFF_CSRM  = OFF_CURM  + (size_t)NM;             // EM
constexpr size_t OFF_OFFSO = OFF_CSRM  + (size_t)EM;             // NO+1
constexpr size_t OFF_CURO  = OFF_OFFSO + (size_t)NO + 1;         // NO
constexpr size_t OFF_CSRO  = OFF_CURO  + (size_t)NO;             // EO
constexpr size_t OFF_PART  = OFF_CSRO  + (size_t)EO;             // 512 (int)
constexpr size_t OFF_WFHI  = OFF_PART  + 512;                    // 65536 floats
constexpr size_t OFF_WFLO  = OFF_WFHI  + 65536;                  // 65536 floats
constexpr size_t WO_Q  = 0, WO_K = 2048, WO_V = 4096, WO_S = 6144, WO_W2 = 8192, WO_W3 = 12288;
// region-A recycling after attn (miniE dead):
constexpr size_t OFF_MFN   = OFF_A;                              // NO*ED
constexpr size_t OFF_AGG   = OFF_MFN   + (size_t)NO * ED;        // NO*ED
constexpr size_t OFF_H     = OFF_AGG   + (size_t)NO * ED;        // NO*HIDD
constexpr size_t OFF_T     = OFF_H     + (size_t)NO * HIDD;      // NO*ED
constexpr size_t OFF_FIN   = OFF_T     + (size_t)NO * ED;        // NO*ED

extern "C" void kernel_launch(void* const* d_in, const int* in_sizes, int n_in,
                              void* d_out, int out_size, void* d_ws, size_t ws_size,
                              hipStream_t stream) {
  const int* desc_tokens = (const int*)d_in[0];
  const int* x_tokens    = (const int*)d_in[1];
  const int* mini_tokens = (const int*)d_in[2];
  const int* src         = (const int*)d_in[3];
  const int* dst         = (const int*)d_in[4];
  const int* mini_src    = (const int*)d_in[5];
  const int* mini_dst    = (const int*)d_in[6];
  const int* mini_batch  = (const int*)d_in[7];
  const int* node_batch  = (const int*)d_in[8];
  const float* desc_table  = (const float*)d_in[9];
  const float* code_table  = (const float*)d_in[10];
  const float* code_table2 = (const float*)d_in[11];
  const float* Wq = (const float*)d_in[12]; const float* bq = (const float*)d_in[13];
  const float* Wk = (const float*)d_in[14]; const float* bk = (const float*)d_in[15];
  const float* Wv = (const float*)d_in[16]; const float* bv = (const float*)d_in[17];
  const float* Wskip = (const float*)d_in[18]; const float* bskip = (const float*)d_in[19];
  const float* W2 = (const float*)d_in[20]; const float* b2 = (const float*)d_in[21];
  const float* W3 = (const float*)d_in[22]; const float* b3 = (const float*)d_in[23];
  const float* Wg = (const float*)d_in[24]; const float* bg = (const float*)d_in[25];

  float* ws = (float*)d_ws;
  float* h_n   = ws + OFF_HN;
  float* stmt  = ws + OFF_STMT;
  unsigned short* miniE_b = (unsigned short*)(ws + OFF_A);    // bf16 [NM][128]
  unsigned short* qhid_b = (unsigned short*)(ws + OFF_QHID);  // q -> hid, bf16
  unsigned short* ctab_b  = (unsigned short*)(ws + OFF_CT);             // bf16 code_table
  unsigned short* ctab2_b = (unsigned short*)(ws + OFF_CT + (size_t)VV * ED / 2);
  unsigned short* kbuf_b = (unsigned short*)(ws + OFF_K);     // k, bf16
  unsigned short* skip_b = kbuf_b + (size_t)NM * ED;          // skip, bf16 (2nd half)
  unsigned short* vbuf_b = (unsigned short*)(ws + OFF_V);     // v, bf16
  float* gate  = ws + OFF_GATE;
  float* gate2 = ws + OFF_GATE2;
  float* fnrep = ws + OFF_FNREP;
  float* dinv  = ws + OFF_DINV;
  int* histm = (int*)(ws + OFF_HISTM);
  int* histo = (int*)(ws + OFF_HISTO);
  int* offsm = (int*)(ws + OFF_OFFSM);
  int* curm  = (int*)(ws + OFF_CURM);
  int* csrm  = (int*)(ws + OFF_CSRM);
  int* offso = (int*)(ws + OFF_OFFSO);
  int* curo  = (int*)(ws + OFF_CURO);
  int* csro  = (int*)(ws + OFF_CSRO);
  int* part  = (int*)(ws + OFF_PART);
  short8* wfhi = (short8*)(ws + OFF_WFHI);
  short8* wflo = (short8*)(ws + OFF_WFLO);
  float* mini_fn = ws + OFF_MFN;
  float* aggb    = ws + OFF_AGG;
  float* hbuf    = ws + OFF_H;
  float* tbuf    = ws + OFF_T;
  float* finalS  = ws + OFF_FIN;
  float* outp    = (float*)d_out;

  // ---- all conversions in ONE launch: 6 weights + 2 tables ----
  WC6 wc;
  wc.w[0] = {Wq,    ED,   ED,   wfhi + WO_Q,  wflo + WO_Q,  (int)WO_Q};
  wc.w[1] = {Wk,    ED,   ED,   wfhi + WO_K,  wflo + WO_K,  (int)WO_K};
  wc.w[2] = {Wv,    ED,   ED,   wfhi + WO_V,  wflo + WO_V,  (int)WO_V};
  wc.w[3] = {Wskip, ED,   ED,   wfhi + WO_S,  wflo + WO_S,  (int)WO_S};
  wc.w[4] = {W2,    ED,   HIDD, wfhi + WO_W2, wflo + WO_W2, (int)WO_W2};
  wc.w[5] = {W3,    HIDD, ED,   wfhi + WO_W3, wflo + WO_W3, (int)WO_W3};
  conv_all_k<<<64 + nblk(2 * VV * ED / 4, 256), 256, 0, stream>>>(
      wc, code_table, ctab_b, code_table2, ctab2_b);

  // ---- CSR build: one memset (adjacent hists), merged hist/scatter, fused dinv ----
  hipMemsetAsync(histm, 0, (size_t)(NM + NO) * 4, stream);
  hist2_k<<<nblk(EM + EO, 256), 256, 0, stream>>>(mini_dst, histm, dst, histo);
  chunk_sum_k<<<NM / 256, 256, 0, stream>>>(histm, part, NM);
  scan_partials_k<<<1, 512, 0, stream>>>(part, NM / 256);
  scan_final_k<<<NM / 256, 256, 0, stream>>>(histm, part, offsm, curm, NM, nullptr);
  chunk_sum_k<<<NO / 256, 256, 0, stream>>>(histo, part, NO);
  scan_partials_k<<<1, 512, 0, stream>>>(part, NO / 256);
  scan_final_k<<<NO / 256, 256, 0, stream>>>(histo, part, offso, curo, NO, dinv);
  scatter2_k<<<nblk(EM + EO, 256), 256, 0, stream>>>(mini_src, mini_dst, curm, csrm,
                                                     src, dst, curo, csro);

  // ---- all three embeddings in one launch ----
  embed_all_k<<<BB / 8 + NO / 8 + NM / 8, 256, 0, stream>>>(
      desc_tokens, desc_table, h_n, x_tokens, ctab2_b, stmt,
      mini_tokens, ctab_b, miniE_b);

  // ---- Q,K,V,Skip projections: zero-LDS direct-global MFMA, grid (4, 640) ----
  QDesc4 g4;
  g4.d[0] = {wfhi + WO_Q, wflo + WO_Q, bq,    qhid_b};
  g4.d[1] = {wfhi + WO_K, wflo + WO_K, bk,    kbuf_b};
  g4.d[2] = {wfhi + WO_V, wflo + WO_V, bv,    vbuf_b};
  g4.d[3] = {wfhi + WO_S, wflo + WO_S, bskip, skip_b};
  { dim3 g(4, NM / 128); mgemm_qkvs4_k<<<g, 256, 0, stream>>>(miniE_b, g4); }

  // ---- fused transformer conv (flash per dst, bf16 streams) + gate ----
  attn_fused_k<<<NM / 4, 128, 0, stream>>>(qhid_b, kbuf_b, vbuf_b, skip_b,
                                           offsm, csrm, Wg, bg, gate);

  // ---- global attention mini -> NO, fused with (x + stmt)*0.5 ----
  gattn_k<true, true><<<NO / 4, 128, 0, stream>>>(qhid_b, gate, mini_batch, NM, stmt, mini_fn);

  // ---- GCN conv 1: agg = A_hat * mini_fn ; h = relu(agg @ W2 + b2) ----
  gcn_gather_k<<<NO / 4, 128, 0, stream>>>(mini_fn, dinv, offso, csro, nullptr, aggb,
                                           nullptr, nullptr, nullptr);
  { dim3 g(HIDD / 128, NO / 128);
    mgemm_k<true><<<g, 256, 0, stream>>>(aggb, wfhi + WO_W2, wflo + WO_W2, b2, hbuf, ED, HIDD); }

  // ---- GCN conv 2: t = h @ W3 ; final = A_hat * t + b3 (+ fused gate2) ----
  { dim3 g(1, NO / 128);
    mgemm_k<false><<<g, 256, 0, stream>>>(hbuf, wfhi + WO_W3, wflo + WO_W3, nullptr, tbuf, HIDD, ED); }
  gcn_gather_k<<<NO / 4, 128, 0, stream>>>(tbuf, dinv, offso, csro, b3, finalS, Wg, bg, gate2);

  // ---- global attention NO -> BB ----
  gattn_k<false, false><<<BB / 4, 128, 0, stream>>>(finalS, gate2, node_batch, NO, nullptr, fnrep);

  // ---- cosine similarity -> d_out [BB] ----
  cosine_k<<<BB, 64, 0, stream>>>(fnrep, h_n, outp);
}

// Round 10
// 378.471 us; speedup vs baseline: 1.0215x; 1.0215x over previous
//
#include <hip/hip_runtime.h>
#include <hip/hip_bf16.h>
#include <math.h>

// Problem dims (fixed by reference)
#define BB   256      // batch
#define LDE  64       // desc tokens len
#define NO   10240    // outer nodes
#define LO   32       // x tokens len
#define NM   81920    // mini nodes
#define LM   16       // mini tokens len
#define EO   81920    // outer edges
#define EM   327680   // mini edges
#define ED   128      // embed dim E
#define HIDD 256      // hidden
#define NH   8        // heads
#define DH   16       // head dim
#define VV   10000    // vocab

static inline int nblk(long long n, int b) { return (int)((n + b - 1) / b); }

typedef __attribute__((ext_vector_type(8))) short short8;
typedef __attribute__((ext_vector_type(4))) float f32x4;

// ---- fp32 <-> bf16 (RNE) helpers ----
static __device__ __forceinline__ unsigned short bf16_rne(float f) {
  unsigned u = __float_as_uint(f);
  return (unsigned short)((u + 0x7fffu + ((u >> 16) & 1u)) >> 16);
}
static __device__ __forceinline__ float bf16_to_f(unsigned short h) {
  return __uint_as_float(((unsigned)h) << 16);
}
static __device__ __forceinline__ float4 b4f(ushort4 h) {
  return make_float4(bf16_to_f(h.x), bf16_to_f(h.y), bf16_to_f(h.z), bf16_to_f(h.w));
}

// ============ merged conversion kernel: 6 weights -> split-bf16 frags, 2 tables -> bf16
struct WC { const float* W; int K, M; short8* hi; short8* lo; int base; };
struct WC6 { WC w[6]; };
__global__ void __launch_bounds__(256)
conv_all_k(WC6 wc, const float* __restrict__ t1, unsigned short* __restrict__ o1,
           const float* __restrict__ t2, unsigned short* __restrict__ o2) {
  if (blockIdx.x < 64) {
    int g = blockIdx.x * 256 + threadIdx.x;   // octet id, 0..16383
    int wi = 0;
    #pragma unroll
    for (int i = 1; i < 6; ++i) if (g >= wc.w[i].base) wi = i;
    const WC c = wc.w[wi];
    int idx = g - c.base;
    int lane = idx & 63;
    int nt = (idx >> 6) % (c.M / 16);
    int kb = (idx >> 6) / (c.M / 16);
    int n = nt * 16 + (lane & 15);
    int k0 = kb * 32 + ((lane >> 4) << 3);
    short8 h, l;
    #pragma unroll
    for (int j = 0; j < 8; ++j) {
      float v = c.W[(size_t)(k0 + j) * c.M + n];
      unsigned short hb = bf16_rne(v);
      h[j] = (short)hb;
      l[j] = (short)bf16_rne(v - bf16_to_f(hb));
    }
    c.hi[idx] = h; c.lo[idx] = l;
  } else {
    int q = (blockIdx.x - 64) * 256 + threadIdx.x;   // quad id
    const int NT = VV * ED / 4;                       // 320000 per table
    if (q < NT) {
      float4 v = *(const float4*)(t1 + (size_t)q * 4);
      *(ushort4*)(o1 + (size_t)q * 4) =
          make_ushort4(bf16_rne(v.x), bf16_rne(v.y), bf16_rne(v.z), bf16_rne(v.w));
    } else if (q < 2 * NT) {
      int q2 = q - NT;
      float4 v = *(const float4*)(t2 + (size_t)q2 * 4);
      *(ushort4*)(o2 + (size_t)q2 * 4) =
          make_ushort4(bf16_rne(v.x), bf16_rne(v.y), bf16_rne(v.z), bf16_rne(v.w));
    }
  }
}

// ---- embedding masked mean body: 256 thr = 8 rows x 32 4-elem lanes ----
template<int L, bool TBF, bool OUTBF>
static __device__ __forceinline__ void embed_body(const int* __restrict__ tokens,
                                                  const void* __restrict__ table,
                                                  void* __restrict__ out, int blk) {
  const int r = threadIdx.x >> 5, lane = threadIdx.x & 31;
  const int n0 = blk * 8;
  __shared__ int toks[8][L];
  for (int i = threadIdx.x; i < 8 * L; i += 256)
    toks[i / L][i % L] = tokens[(size_t)n0 * L + i];
  __syncthreads();
  float4 acc = make_float4(0.f, 0.f, 0.f, 0.f);
  int cnt = 0;
  #pragma unroll
  for (int l = 0; l < L; ++l) {
    int t = toks[r][l];
    float4 v;
    if (TBF) v = b4f(*((const ushort4*)((const unsigned short*)table + (size_t)t * ED + lane * 4)));
    else     v = *(const float4*)((const float*)table + (size_t)t * ED + lane * 4);
    float msk = (t != 0) ? 1.f : 0.f;
    cnt += (t != 0);
    acc.x = fmaf(msk, v.x, acc.x); acc.y = fmaf(msk, v.y, acc.y);
    acc.z = fmaf(msk, v.z, acc.z); acc.w = fmaf(msk, v.w, acc.w);
  }
  float inv = 1.f / (float)(cnt > 0 ? cnt : 1);
  acc.x *= inv; acc.y *= inv; acc.z *= inv; acc.w *= inv;
  if (OUTBF)
    *(ushort4*)((unsigned short*)out + (size_t)(n0 + r) * ED + lane * 4) =
        make_ushort4(bf16_rne(acc.x), bf16_rne(acc.y), bf16_rne(acc.z), bf16_rne(acc.w));
  else
    *(float4*)((float*)out + (size_t)(n0 + r) * ED + lane * 4) = acc;
}

// all three embeddings in one launch: [0,32) desc | [32,1312) x | [1312,11552) mini
__global__ void __launch_bounds__(256)
embed_all_k(const int* __restrict__ desc_tokens, const float* __restrict__ desc_table,
            float* __restrict__ h_n,
            const int* __restrict__ x_tokens, const unsigned short* __restrict__ ctab2,
            float* __restrict__ stmt,
            const int* __restrict__ mini_tokens, const unsigned short* __restrict__ ctab,
            unsigned short* __restrict__ miniE) {
  int b = blockIdx.x;
  if (b < BB / 8) embed_body<LDE, false, false>(desc_tokens, desc_table, h_n, b);
  else if (b < BB / 8 + NO / 8) embed_body<LO, true, false>(x_tokens, ctab2, stmt, b - BB / 8);
  else embed_body<LM, true, true>(mini_tokens, ctab, miniE, b - BB / 8 - NO / 8);
}

// ========== QKVS GEMM v5: direct-global A-fragments + LDS-transposed WIDE stores =====
// Epilogue: per-wave private 16x68-ushort LDS patch; D-tiles packed (bias added) then
// re-read as 8B chunks -> uint4 global stores (16 B/lane, full 64B lines).
struct QDesc { const short8* bh; const short8* bl; const float* bias; unsigned short* C; };
struct QDesc4 { QDesc d[4]; };

__global__ void __launch_bounds__(256)
mgemm_qkvs5_k(const unsigned short* __restrict__ Ab, QDesc4 g4) {
  const QDesc d = g4.d[blockIdx.x];
  const int n0 = blockIdx.y * 128;
  __shared__ unsigned short Tl[4][16][68];   // wave-private patches; +4 pad = conflict-free writes
  const int tid = threadIdx.x;
  const int w = tid >> 6, lane = tid & 63;
  const int wm = (w & 1) * 4, wn = (w >> 1) * 4;
  const int r = lane & 15, qd = lane >> 4;
  f32x4 acc[4][4];
  #pragma unroll
  for (int i = 0; i < 4; ++i)
    #pragma unroll
    for (int j = 0; j < 4; ++j) acc[i][j] = (f32x4){0.f, 0.f, 0.f, 0.f};
  #pragma unroll
  for (int kb = 0; kb < 4; ++kb) {
    short8 bh[4], bl[4];
    #pragma unroll
    for (int j = 0; j < 4; ++j) {
      size_t bi = ((size_t)kb * 8 + wn + j) * 64 + lane;
      bh[j] = d.bh[bi]; bl[j] = d.bl[bi];
    }
    short8 a[4];
    #pragma unroll
    for (int i = 0; i < 4; ++i)
      a[i] = *(const short8*)(Ab + (size_t)(n0 + (wm + i) * 16 + r) * ED + kb * 32 + qd * 8);
    #pragma unroll
    for (int i = 0; i < 4; ++i)
      #pragma unroll
      for (int j = 0; j < 4; ++j) {
        acc[i][j] = __builtin_amdgcn_mfma_f32_16x16x32_bf16(a[i], bh[j], acc[i][j], 0, 0, 0);
        acc[i][j] = __builtin_amdgcn_mfma_f32_16x16x32_bf16(a[i], bl[j], acc[i][j], 0, 0, 0);
      }
  }
  // epilogue: one 16-row i-tile at a time through the wave-private LDS patch
  const int r8 = lane >> 3, c8 = lane & 7;
  const int growbase = n0 + (w & 1) * 64;
  const int gcol = (w >> 1) * 64 + c8 * 8;     // ushort col of this lane's 16B chunk
  #pragma unroll
  for (int i = 0; i < 4; ++i) {
    #pragma unroll
    for (int j = 0; j < 4; ++j) {
      float bv = d.bias[(wn + j) * 16 + r];
      #pragma unroll
      for (int rr = 0; rr < 4; ++rr)
        Tl[w][qd * 4 + rr][j * 16 + r] = bf16_rne(acc[i][j][rr] + bv);
    }
    #pragma unroll
    for (int it = 0; it < 2; ++it) {
      int lrow = it * 8 + r8;
      const unsigned short* lp = &Tl[w][lrow][c8 * 8];
      uint2 u0 = *(const uint2*)lp;
      uint2 u1 = *(const uint2*)(lp + 4);
      *(uint4*)(d.C + (size_t)(growbase + i * 16 + lrow) * ED + gcol) =
          make_uint4(u0.x, u0.y, u1.x, u1.y);
    }
  }
}

// ================= MFMA GEMM (fp32 A, split-bf16 3-term): W2 / W3 path ==============
template<bool RELU>
__global__ void __launch_bounds__(256)
mgemm_k(const float* __restrict__ A, const short8* __restrict__ Bh,
        const short8* __restrict__ Bl, const float* __restrict__ bias,
        float* C, int K, int M) {
  __shared__ short8 Ah[8][64];
  __shared__ short8 Al[8][64];
  const int bm0 = blockIdx.y * 128, bn0 = blockIdx.x * 128;
  const int tid = threadIdx.x;
  const int w = tid >> 6, lane = tid & 63;
  const int wm = (w & 1) * 4, wn = (w >> 1) * 4;
  const int NTm = M / 16;
  f32x4 acc[4][4];
  #pragma unroll
  for (int i = 0; i < 4; ++i)
    #pragma unroll
    for (int j = 0; j < 4; ++j) acc[i][j] = (f32x4){0.f, 0.f, 0.f, 0.f};
  const int kbn = K / 32;
  for (int kb = 0; kb < kbn; ++kb) {
    __syncthreads();
    #pragma unroll
    for (int it = 0; it < 2; ++it) {
      int u = tid + it * 256;
      int mt = u >> 6, l = u & 63;
      int m = bm0 + mt * 16 + (l & 15);
      int k = kb * 32 + ((l >> 4) << 3);
      const float* ap = A + (size_t)m * K + k;
      float4 v0 = *(const float4*)ap;
      float4 v1 = *(const float4*)(ap + 4);
      float f[8] = {v0.x, v0.y, v0.z, v0.w, v1.x, v1.y, v1.z, v1.w};
      short8 hh, ll;
      #pragma unroll
      for (int j = 0; j < 8; ++j) {
        unsigned short hb = bf16_rne(f[j]);
        hh[j] = (short)hb;
        ll[j] = (short)bf16_rne(f[j] - bf16_to_f(hb));
      }
      Ah[mt][l] = hh; Al[mt][l] = ll;
    }
    __syncthreads();
    short8 bh[4], bl[4];
    #pragma unroll
    for (int j = 0; j < 4; ++j) {
      size_t bi = ((size_t)kb * NTm + (bn0 >> 4) + wn + j) * 64 + lane;
      bh[j] = Bh[bi]; bl[j] = Bl[bi];
    }
    #pragma unroll
    for (int i = 0; i < 4; ++i) {
      short8 ah = Ah[wm + i][lane];
      short8 al = Al[wm + i][lane];
      #pragma unroll
      for (int j = 0; j < 4; ++j) {
        acc[i][j] = __builtin_amdgcn_mfma_f32_16x16x32_bf16(ah, bh[j], acc[i][j], 0, 0, 0);
        acc[i][j] = __builtin_amdgcn_mfma_f32_16x16x32_bf16(ah, bl[j], acc[i][j], 0, 0, 0);
        acc[i][j] = __builtin_amdgcn_mfma_f32_16x16x32_bf16(al, bh[j], acc[i][j], 0, 0, 0);
      }
    }
  }
  const int q = lane >> 4, c = lane & 15;
  #pragma unroll
  for (int i = 0; i < 4; ++i)
    #pragma unroll
    for (int j = 0; j < 4; ++j) {
      int col = bn0 + (wn + j) * 16 + c;
      float bv = bias ? bias[col] : 0.f;
      #pragma unroll
      for (int rr = 0; rr < 4; ++rr) {
        int row = bm0 + (wm + i) * 16 + q * 4 + rr;
        float v = acc[i][j][rr] + bv;
        if (RELU) v = fmaxf(v, 0.f);
        C[(size_t)row * M + col] = v;
      }
    }
}

// ================= CSR build (merged scan chain) =================
__global__ void hist2_k(const int* __restrict__ dm, int* __restrict__ hm,
                        const int* __restrict__ dd, int* __restrict__ ho) {
  int e = blockIdx.x * 256 + threadIdx.x;
  if (e < EM) atomicAdd(&hm[dm[e]], 1);
  else { int e2 = e - EM; if (e2 < EO) atomicAdd(&ho[dd[e2]], 1); }
}
// hist = concat(histm, histo) — one launch over (NM+NO)/256 = 360 blocks
__global__ void chunk_sum_k(const int* __restrict__ hist, int* __restrict__ partials, int N) {
  __shared__ int sd[256];
  int i = blockIdx.x * 256 + threadIdx.x;
  sd[threadIdx.x] = (i < N) ? hist[i] : 0;
  __syncthreads();
  for (int s = 128; s > 0; s >>= 1) {
    if (threadIdx.x < s) sd[threadIdx.x] += sd[threadIdx.x + s];
    __syncthreads();
  }
  if (threadIdx.x == 0) partials[blockIdx.x] = sd[0];
}
// two blocks: block0 scans part[0..NM/256), block1 scans part[NM/256..NM/256+NO/256)
__global__ void scan_partials2_k(int* __restrict__ p) {
  __shared__ int sd[512];
  int base = (blockIdx.x == 0) ? 0 : NM / 256;
  int B    = (blockIdx.x == 0) ? NM / 256 : NO / 256;
  int t = threadIdx.x;
  int v = (t < B) ? p[base + t] : 0;
  sd[t] = v; __syncthreads();
  for (int off = 1; off < 512; off <<= 1) {
    int a = (t >= off) ? sd[t - off] : 0;
    __syncthreads();
    sd[t] += a;
    __syncthreads();
  }
  if (t < B) p[base + t] = sd[t] - v;   // exclusive
}
// final scan over concat hist; branches per element into mini/outer outputs; fused dinv
__global__ void scan_final2_k(const int* __restrict__ hist, const int* __restrict__ partials,
                              int* __restrict__ offsm, int* __restrict__ curm,
                              int* __restrict__ offso, int* __restrict__ curo,
                              float* __restrict__ dinv) {
  __shared__ int sd[256];
  int i = blockIdx.x * 256 + threadIdx.x;
  int v = hist[i];
  sd[threadIdx.x] = v; __syncthreads();
  for (int off = 1; off < 256; off <<= 1) {
    int a = (threadIdx.x >= off) ? sd[threadIdx.x - off] : 0;
    __syncthreads();
    sd[threadIdx.x] += a;
    __syncthreads();
  }
  int excl = sd[threadIdx.x] - v + partials[blockIdx.x];
  if (i < NM) {
    offsm[i] = excl; curm[i] = excl;
    if (i == NM - 1) offsm[NM] = excl + v;
  } else {
    int i2 = i - NM;
    offso[i2] = excl; curo[i2] = excl;
    if (i2 == NO - 1) offso[NO] = excl + v;
    dinv[i2] = 1.f / sqrtf(1.f + (float)v);
  }
}
__global__ void scatter2_k(const int* __restrict__ sm, const int* __restrict__ dm,
                           int* __restrict__ cm, int* __restrict__ km,
                           const int* __restrict__ so, const int* __restrict__ dd,
                           int* __restrict__ co, int* __restrict__ ko) {
  int e = blockIdx.x * 256 + threadIdx.x;
  if (e < EM) {
    int pos = atomicAdd(&cm[dm[e]], 1);
    km[pos] = sm[e];
  } else {
    int e2 = e - EM;
    if (e2 < EO) {
      int pos = atomicAdd(&co[dd[e2]], 1);
      ko[pos] = so[e2];
    }
  }
}

// ============ fused TransformerConv (bf16 streams): flash per dst + skip + gate ======
__global__ void __launch_bounds__(128)
attn_fused_k(unsigned short* qh, const unsigned short* __restrict__ kk,
             const unsigned short* __restrict__ vv, const unsigned short* __restrict__ skip,
             const int* __restrict__ offs, const int* __restrict__ csr,
             const float* __restrict__ Wg, const float* __restrict__ bg,
             float* __restrict__ gateOut) {
  const int g = threadIdx.x >> 5, lane = threadIdx.x & 31;
  const int n = blockIdx.x * 4 + g;
  float4 q = b4f(*(const ushort4*)(qh + (size_t)n * ED + lane * 4));
  int lo = offs[n], hi = offs[n + 1];
  float4 O = make_float4(0.f, 0.f, 0.f, 0.f);
  float m = -INFINITY, l = 0.f;
  for (int e = lo; e < hi; ++e) {
    int s = csr[e];
    float4 kt = b4f(*(const ushort4*)(kk + (size_t)s * ED + lane * 4));
    float4 vt = b4f(*(const ushort4*)(vv + (size_t)s * ED + lane * 4));
    float p = q.x * kt.x + q.y * kt.y + q.z * kt.z + q.w * kt.w;
    p += __shfl_xor(p, 1, 64);
    p += __shfl_xor(p, 2, 64);
    float sc = p * 0.25f;               // 1/sqrt(Dh)
    float mn = fmaxf(m, sc);
    float scale = __expf(m - mn);       // exp(-inf)=0 handles first edge
    float pe = __expf(sc - mn);
    l = l * scale + pe;
    O.x = O.x * scale + pe * vt.x; O.y = O.y * scale + pe * vt.y;
    O.z = O.z * scale + pe * vt.z; O.w = O.w * scale + pe * vt.w;
    m = mn;
  }
  float inv = 1.f / (l + 1e-16f);
  float4 sk = b4f(*(const ushort4*)(skip + (size_t)n * ED + lane * 4));
  float4 out = make_float4(O.x * inv + sk.x, O.y * inv + sk.y,
                           O.z * inv + sk.z, O.w * inv + sk.w);
  *(ushort4*)(qh + (size_t)n * ED + lane * 4) =
      make_ushort4(bf16_rne(out.x), bf16_rne(out.y), bf16_rne(out.z), bf16_rne(out.w));
  float4 wg = *(const float4*)(Wg + lane * 4);
  float ps = out.x * wg.x + out.y * wg.y + out.z * wg.z + out.w * wg.w;
  #pragma unroll
  for (int o = 1; o <= 16; o <<= 1) ps += __shfl_xor(ps, o, 64);
  if (lane == 0) gateOut[n] = ps + bg[0];
}

// ============ GCN gather (fp32): 4 nodes x 32 float4-lanes ============
__global__ void __launch_bounds__(128)
gcn_gather_k(const float* __restrict__ x, const float* __restrict__ dinv,
             const int* __restrict__ offs, const int* __restrict__ csr,
             const float* __restrict__ bias, float* __restrict__ out,
             const float* __restrict__ Wg, const float* __restrict__ bg,
             float* __restrict__ gateOut) {
  const int g = threadIdx.x >> 5, lane = threadIdx.x & 31;
  const int n = blockIdx.x * 4 + g;
  float di = dinv[n];
  float4 xs = *(const float4*)(x + (size_t)n * ED + lane * 4);
  float w0 = di * di;
  float4 acc = make_float4(w0 * xs.x, w0 * xs.y, w0 * xs.z, w0 * xs.w);
  int lo = offs[n], hi = offs[n + 1];
  for (int e = lo; e < hi; ++e) {
    int s = csr[e];
    float w = di * dinv[s];
    float4 v = *(const float4*)(x + (size_t)s * ED + lane * 4);
    acc.x = fmaf(w, v.x, acc.x); acc.y = fmaf(w, v.y, acc.y);
    acc.z = fmaf(w, v.z, acc.z); acc.w = fmaf(w, v.w, acc.w);
  }
  if (bias) {
    float4 b4 = *(const float4*)(bias + lane * 4);
    acc.x += b4.x; acc.y += b4.y; acc.z += b4.z; acc.w += b4.w;
  }
  *(float4*)(out + (size_t)n * ED + lane * 4) = acc;
  if (gateOut) {
    float4 wg = *(const float4*)(Wg + lane * 4);
    float ps = acc.x * wg.x + acc.y * wg.y + acc.z * wg.z + acc.w * wg.w;
    #pragma unroll
    for (int o = 1; o <= 16; o <<= 1) ps += __shfl_xor(ps, o, 64);
    if (lane == 0) gateOut[n] = ps + bg[0];
  }
}

// ============ global attention over contiguous (sorted) segments ============
static __device__ __forceinline__ int lower_bound_d(const int* a, int n, int key) {
  int lo = 0, hi = n;
  while (lo < hi) { int mid = (lo + hi) >> 1; if (a[mid] < key) lo = mid + 1; else hi = mid; }
  return lo;
}
template<bool COMBINE, bool XBF>
__global__ void __launch_bounds__(128)
gattn_k(const void* __restrict__ xv, const float* __restrict__ gate,
        const int* __restrict__ seg, int Ntot,
        const float* __restrict__ other, float* __restrict__ out) {
  const int g = threadIdx.x >> 5, lane = threadIdx.x & 31;
  const int n = blockIdx.x * 4 + g;
  __shared__ int sh[4][2];
  if (lane == 0) {
    sh[g][0] = lower_bound_d(seg, Ntot, n);
    sh[g][1] = lower_bound_d(seg, Ntot, n + 1);
  }
  __syncthreads();
  int lo = sh[g][0], hi = sh[g][1];
  float m = -INFINITY;
  for (int j = lo; j < hi; ++j) m = fmaxf(m, gate[j]);
  float ssum = 0.f;
  for (int j = lo; j < hi; ++j) ssum += __expf(gate[j] - m);
  float inv = 1.f / (ssum + 1e-16f);
  float4 acc = make_float4(0.f, 0.f, 0.f, 0.f);
  for (int j = lo; j < hi; ++j) {
    float a = __expf(gate[j] - m) * inv;
    float4 v;
    if (XBF) v = b4f(*((const ushort4*)((const unsigned short*)xv + (size_t)j * ED + lane * 4)));
    else     v = *((const float4*)((const float*)xv + (size_t)j * ED) + lane);
    acc.x = fmaf(a, v.x, acc.x); acc.y = fmaf(a, v.y, acc.y);
    acc.z = fmaf(a, v.z, acc.z); acc.w = fmaf(a, v.w, acc.w);
  }
  if (COMBINE) {
    float4 o4 = *(const float4*)(other + (size_t)n * ED + lane * 4);
    acc.x = (acc.x + o4.x) * 0.5f; acc.y = (acc.y + o4.y) * 0.5f;
    acc.z = (acc.z + o4.z) * 0.5f; acc.w = (acc.w + o4.w) * 0.5f;
  }
  *(float4*)(out + (size_t)n * ED + lane * 4) = acc;
}

// ============ final global attention NO->BB with cosine fused (no fnrep roundtrip) ====
__global__ void __launch_bounds__(128)
gattn_cos_k(const float* __restrict__ x, const float* __restrict__ gate,
            const int* __restrict__ seg, int Ntot,
            const float* __restrict__ hn, float* __restrict__ outp) {
  const int g = threadIdx.x >> 5, lane = threadIdx.x & 31;
  const int n = blockIdx.x * 4 + g;
  __shared__ int sh[4][2];
  if (lane == 0) {
    sh[g][0] = lower_bound_d(seg, Ntot, n);
    sh[g][1] = lower_bound_d(seg, Ntot, n + 1);
  }
  __syncthreads();
  int lo = sh[g][0], hi = sh[g][1];
  float m = -INFINITY;
  for (int j = lo; j < hi; ++j) m = fmaxf(m, gate[j]);
  float ssum = 0.f;
  for (int j = lo; j < hi; ++j) ssum += __expf(gate[j] - m);
  float inv = 1.f / (ssum + 1e-16f);
  float4 acc = make_float4(0.f, 0.f, 0.f, 0.f);
  for (int j = lo; j < hi; ++j) {
    float a = __expf(gate[j] - m) * inv;
    float4 v = *((const float4*)(x + (size_t)j * ED) + lane);
    acc.x = fmaf(a, v.x, acc.x); acc.y = fmaf(a, v.y, acc.y);
    acc.z = fmaf(a, v.z, acc.z); acc.w = fmaf(a, v.w, acc.w);
  }
  float4 hv = *(const float4*)(hn + (size_t)n * ED + lane * 4);
  float dot = acc.x * hv.x + acc.y * hv.y + acc.z * hv.z + acc.w * hv.w;
  float na  = acc.x * acc.x + acc.y * acc.y + acc.z * acc.z + acc.w * acc.w;
  float nb  = hv.x * hv.x + hv.y * hv.y + hv.z * hv.z + hv.w * hv.w;
  #pragma unroll
  for (int o = 1; o <= 16; o <<= 1) {
    dot += __shfl_xor(dot, o, 64);
    na  += __shfl_xor(na,  o, 64);
    nb  += __shfl_xor(nb,  o, 64);
  }
  if (lane == 0)
    outp[n] = dot / (fmaxf(sqrtf(na), 1e-8f) * fmaxf(sqrtf(nb), 1e-8f));
}

// ---- workspace layout (4-byte element offsets) ----
constexpr size_t OFF_HN    = 0;                                  // BB*ED
constexpr size_t OFF_STMT  = OFF_HN    + (size_t)BB * ED;        // NO*ED
constexpr size_t OFF_A     = OFF_STMT  + (size_t)NO * ED;        // NM*ED (miniE bf16 -> recycled)
constexpr size_t OFF_QHID  = OFF_A     + (size_t)NM * ED;        // NM*ED floats (bf16 q->hid in 1st half)
constexpr size_t OFF_CT    = OFF_QHID  + (size_t)NM * ED / 2;    // 2nd half of QHID: bf16 tables
constexpr size_t OFF_K     = OFF_QHID  + (size_t)NM * ED;        // NM*ED floats (bf16 k + bf16 skip)
constexpr size_t OFF_V     = OFF_K     + (size_t)NM * ED;        // NM*ED floats (bf16 v in 1st half)
constexpr size_t T0        = OFF_V     + (size_t)NM * ED;
constexpr size_t OFF_GATE  = T0;                                 // NM
constexpr size_t OFF_GATE2 = OFF_GATE  + (size_t)NM;             // NO
constexpr size_t OFF_DINV  = OFF_GATE2 + (size_t)NO;             // NO
constexpr size_t OFF_HISTM = OFF_DINV  + (size_t)NO;             // NM (int)
constexpr size_t OFF_HISTO = OFF_HISTM + (size_t)NM;             // NO (adjacent -> concat scan)
constexpr size_t OFF_OFFSM = OFF_HISTO + (size_t)NO;             // NM+1
constexpr size_t OFF_CURM  = OFF_OFFSM + (size_t)NM + 1;         // NM
constexpr size_t OFF_CSRM  = OFF_CURM  + (size_t)NM;             // EM
constexpr size_t OFF_OFFSO = OFF_CSRM  + (size_t)EM;             // NO+1
constexpr size_t OFF_CURO  = OFF_OFFSO + (size_t)NO + 1;         // NO
constexpr size_t OFF_CSRO  = OFF_CURO  + (size_t)NO;             // EO
constexpr size_t OFF_PART  = OFF_CSRO  + (size_t)EO;             // 512 (int)
constexpr size_t OFF_WFHI  = OFF_PART  + 512;                    // 65536 floats
constexpr size_t OFF_WFLO  = OFF_WFHI  + 65536;                  // 65536 floats
constexpr size_t WO_Q  = 0, WO_K = 2048, WO_V = 4096, WO_S = 6144, WO_W2 = 8192, WO_W3 = 12288;
// region-A recycling after attn (miniE dead):
constexpr size_t OFF_MFN   = OFF_A;                              // NO*ED
constexpr size_t OFF_AGG   = OFF_MFN   + (size_t)NO * ED;        // NO*ED
constexpr size_t OFF_H     = OFF_AGG   + (size_t)NO * ED;        // NO*HIDD
constexpr size_t OFF_T     = OFF_H     + (size_t)NO * HIDD;      // NO*ED
constexpr size_t OFF_FIN   = OFF_T     + (size_t)NO * ED;        // NO*ED

extern "C" void kernel_launch(void* const* d_in, const int* in_sizes, int n_in,
                              void* d_out, int out_size, void* d_ws, size_t ws_size,
                              hipStream_t stream) {
  const int* desc_tokens = (const int*)d_in[0];
  const int* x_tokens    = (const int*)d_in[1];
  const int* mini_tokens = (const int*)d_in[2];
  const int* src         = (const int*)d_in[3];
  const int* dst         = (const int*)d_in[4];
  const int* mini_src    = (const int*)d_in[5];
  const int* mini_dst    = (const int*)d_in[6];
  const int* mini_batch  = (const int*)d_in[7];
  const int* node_batch  = (const int*)d_in[8];
  const float* desc_table  = (const float*)d_in[9];
  const float* code_table  = (const float*)d_in[10];
  const float* code_table2 = (const float*)d_in[11];
  const float* Wq = (const float*)d_in[12]; const float* bq = (const float*)d_in[13];
  const float* Wk = (const float*)d_in[14]; const float* bk = (const float*)d_in[15];
  const float* Wv = (const float*)d_in[16]; const float* bv = (const float*)d_in[17];
  const float* Wskip = (const float*)d_in[18]; const float* bskip = (const float*)d_in[19];
  const float* W2 = (const float*)d_in[20]; const float* b2 = (const float*)d_in[21];
  const float* W3 = (const float*)d_in[22]; const float* b3 = (const float*)d_in[23];
  const float* Wg = (const float*)d_in[24]; const float* bg = (const float*)d_in[25];

  float* ws = (float*)d_ws;
  float* h_n   = ws + OFF_HN;
  float* stmt  = ws + OFF_STMT;
  unsigned short* miniE_b = (unsigned short*)(ws + OFF_A);    // bf16 [NM][128]
  unsigned short* qhid_b = (unsigned short*)(ws + OFF_QHID);  // q -> hid, bf16
  unsigned short* ctab_b  = (unsigned short*)(ws + OFF_CT);             // bf16 code_table
  unsigned short* ctab2_b = (unsigned short*)(ws + OFF_CT + (size_t)VV * ED / 2);
  unsigned short* kbuf_b = (unsigned short*)(ws + OFF_K);     // k, bf16
  unsigned short* skip_b = kbuf_b + (size_t)NM * ED;          // skip, bf16 (2nd half)
  unsigned short* vbuf_b = (unsigned short*)(ws + OFF_V);     // v, bf16
  float* gate  = ws + OFF_GATE;
  float* gate2 = ws + OFF_GATE2;
  float* dinv  = ws + OFF_DINV;
  int* histm = (int*)(ws + OFF_HISTM);
  int* histo = (int*)(ws + OFF_HISTO);
  int* offsm = (int*)(ws + OFF_OFFSM);
  int* curm  = (int*)(ws + OFF_CURM);
  int* csrm  = (int*)(ws + OFF_CSRM);
  int* offso = (int*)(ws + OFF_OFFSO);
  int* curo  = (int*)(ws + OFF_CURO);
  int* csro  = (int*)(ws + OFF_CSRO);
  int* part  = (int*)(ws + OFF_PART);
  short8* wfhi = (short8*)(ws + OFF_WFHI);
  short8* wflo = (short8*)(ws + OFF_WFLO);
  float* mini_fn = ws + OFF_MFN;
  float* aggb    = ws + OFF_AGG;
  float* hbuf    = ws + OFF_H;
  float* tbuf    = ws + OFF_T;
  float* finalS  = ws + OFF_FIN;
  float* outp    = (float*)d_out;

  // ---- all conversions in ONE launch: 6 weights + 2 tables ----
  WC6 wc;
  wc.w[0] = {Wq,    ED,   ED,   wfhi + WO_Q,  wflo + WO_Q,  (int)WO_Q};
  wc.w[1] = {Wk,    ED,   ED,   wfhi + WO_K,  wflo + WO_K,  (int)WO_K};
  wc.w[2] = {Wv,    ED,   ED,   wfhi + WO_V,  wflo + WO_V,  (int)WO_V};
  wc.w[3] = {Wskip, ED,   ED,   wfhi + WO_S,  wflo + WO_S,  (int)WO_S};
  wc.w[4] = {W2,    ED,   HIDD, wfhi + WO_W2, wflo + WO_W2, (int)WO_W2};
  wc.w[5] = {W3,    HIDD, ED,   wfhi + WO_W3, wflo + WO_W3, (int)WO_W3};
  conv_all_k<<<64 + nblk(2 * VV * ED / 4, 256), 256, 0, stream>>>(
      wc, code_table, ctab_b, code_table2, ctab2_b);

  // ---- CSR build: merged hist/scatter + single concat scan chain + fused dinv ----
  hipMemsetAsync(histm, 0, (size_t)(NM + NO) * 4, stream);
  hist2_k<<<nblk(EM + EO, 256), 256, 0, stream>>>(mini_dst, histm, dst, histo);
  chunk_sum_k<<<(NM + NO) / 256, 256, 0, stream>>>(histm, part, NM + NO);
  scan_partials2_k<<<2, 512, 0, stream>>>(part);
  scan_final2_k<<<(NM + NO) / 256, 256, 0, stream>>>(histm, part, offsm, curm,
                                                     offso, curo, dinv);
  scatter2_k<<<nblk(EM + EO, 256), 256, 0, stream>>>(mini_src, mini_dst, curm, csrm,
                                                     src, dst, curo, csro);

  // ---- all three embeddings in one launch ----
  embed_all_k<<<BB / 8 + NO / 8 + NM / 8, 256, 0, stream>>>(
      desc_tokens, desc_table, h_n, x_tokens, ctab2_b, stmt,
      mini_tokens, ctab_b, miniE_b);

  // ---- Q,K,V,Skip projections: direct-global A frags + wide LDS-transposed stores ----
  QDesc4 g4;
  g4.d[0] = {wfhi + WO_Q, wflo + WO_Q, bq,    qhid_b};
  g4.d[1] = {wfhi + WO_K, wflo + WO_K, bk,    kbuf_b};
  g4.d[2] = {wfhi + WO_V, wflo + WO_V, bv,    vbuf_b};
  g4.d[3] = {wfhi + WO_S, wflo + WO_S, bskip, skip_b};
  { dim3 g(4, NM / 128); mgemm_qkvs5_k<<<g, 256, 0, stream>>>(miniE_b, g4); }

  // ---- fused transformer conv (flash per dst, bf16 streams) + gate ----
  attn_fused_k<<<NM / 4, 128, 0, stream>>>(qhid_b, kbuf_b, vbuf_b, skip_b,
                                           offsm, csrm, Wg, bg, gate);

  // ---- global attention mini -> NO, fused with (x + stmt)*0.5 ----
  gattn_k<true, true><<<NO / 4, 128, 0, stream>>>(qhid_b, gate, mini_batch, NM, stmt, mini_fn);

  // ---- GCN conv 1: agg = A_hat * mini_fn ; h = relu(agg @ W2 + b2) ----
  gcn_gather_k<<<NO / 4, 128, 0, stream>>>(mini_fn, dinv, offso, csro, nullptr, aggb,
                                           nullptr, nullptr, nullptr);
  { dim3 g(HIDD / 128, NO / 128);
    mgemm_k<true><<<g, 256, 0, stream>>>(aggb, wfhi + WO_W2, wflo + WO_W2, b2, hbuf, ED, HIDD); }

  // ---- GCN conv 2: t = h @ W3 ; final = A_hat * t + b3 (+ fused gate2) ----
  { dim3 g(1, NO / 128);
    mgemm_k<false><<<g, 256, 0, stream>>>(hbuf, wfhi + WO_W3, wflo + WO_W3, nullptr, tbuf, HIDD, ED); }
  gcn_gather_k<<<NO / 4, 128, 0, stream>>>(tbuf, dinv, offso, csro, b3, finalS, Wg, bg, gate2);

  // ---- global attention NO -> BB with fused cosine -> d_out [BB] ----
  gattn_cos_k<<<BB / 4, 128, 0, stream>>>(finalS, gate2, node_batch, NO, h_n, outp);
}

// Round 11
// 372.133 us; speedup vs baseline: 1.0389x; 1.0170x over previous
//
#include <hip/hip_runtime.h>
#include <hip/hip_bf16.h>
#include <math.h>

// Problem dims (fixed by reference)
#define BB   256      // batch
#define LDE  64       // desc tokens len
#define NO   10240    // outer nodes
#define LO   32       // x tokens len
#define NM   81920    // mini nodes
#define LM   16       // mini tokens len
#define EO   81920    // outer edges
#define EM   327680   // mini edges
#define ED   128      // embed dim E
#define HIDD 256      // hidden
#define NH   8        // heads
#define DH   16       // head dim
#define VV   10000    // vocab

static inline int nblk(long long n, int b) { return (int)((n + b - 1) / b); }

typedef __attribute__((ext_vector_type(8))) short short8;
typedef __attribute__((ext_vector_type(4))) float f32x4;

// ---- fp32 <-> bf16 (RNE) helpers ----
static __device__ __forceinline__ unsigned short bf16_rne(float f) {
  unsigned u = __float_as_uint(f);
  return (unsigned short)((u + 0x7fffu + ((u >> 16) & 1u)) >> 16);
}
static __device__ __forceinline__ float bf16_to_f(unsigned short h) {
  return __uint_as_float(((unsigned)h) << 16);
}
static __device__ __forceinline__ float4 b4f(ushort4 h) {
  return make_float4(bf16_to_f(h.x), bf16_to_f(h.y), bf16_to_f(h.z), bf16_to_f(h.w));
}

// ============ merged conversion kernel: 6 weights -> split-bf16 frags, 2 tables -> bf16
struct WC { const float* W; int K, M; short8* hi; short8* lo; int base; };
struct WC6 { WC w[6]; };
__global__ void __launch_bounds__(256)
conv_all_k(WC6 wc, const float* __restrict__ t1, unsigned short* __restrict__ o1,
           const float* __restrict__ t2, unsigned short* __restrict__ o2) {
  if (blockIdx.x < 64) {
    int g = blockIdx.x * 256 + threadIdx.x;   // octet id, 0..16383
    int wi = 0;
    #pragma unroll
    for (int i = 1; i < 6; ++i) if (g >= wc.w[i].base) wi = i;
    const WC c = wc.w[wi];
    int idx = g - c.base;
    int lane = idx & 63;
    int nt = (idx >> 6) % (c.M / 16);
    int kb = (idx >> 6) / (c.M / 16);
    int n = nt * 16 + (lane & 15);
    int k0 = kb * 32 + ((lane >> 4) << 3);
    short8 h, l;
    #pragma unroll
    for (int j = 0; j < 8; ++j) {
      float v = c.W[(size_t)(k0 + j) * c.M + n];
      unsigned short hb = bf16_rne(v);
      h[j] = (short)hb;
      l[j] = (short)bf16_rne(v - bf16_to_f(hb));
    }
    c.hi[idx] = h; c.lo[idx] = l;
  } else {
    int q = (blockIdx.x - 64) * 256 + threadIdx.x;   // quad id
    const int NT = VV * ED / 4;                       // 320000 per table
    if (q < NT) {
      float4 v = *(const float4*)(t1 + (size_t)q * 4);
      *(ushort4*)(o1 + (size_t)q * 4) =
          make_ushort4(bf16_rne(v.x), bf16_rne(v.y), bf16_rne(v.z), bf16_rne(v.w));
    } else if (q < 2 * NT) {
      int q2 = q - NT;
      float4 v = *(const float4*)(t2 + (size_t)q2 * 4);
      *(ushort4*)(o2 + (size_t)q2 * 4) =
          make_ushort4(bf16_rne(v.x), bf16_rne(v.y), bf16_rne(v.z), bf16_rne(v.w));
    }
  }
}

// ---- embedding masked mean body: 256 thr = 8 rows x 32 4-elem lanes ----
template<int L, bool TBF, bool OUTBF>
static __device__ __forceinline__ void embed_body(const int* __restrict__ tokens,
                                                  const void* __restrict__ table,
                                                  void* __restrict__ out, int blk) {
  const int r = threadIdx.x >> 5, lane = threadIdx.x & 31;
  const int n0 = blk * 8;
  __shared__ int toks[8][L];
  for (int i = threadIdx.x; i < 8 * L; i += 256)
    toks[i / L][i % L] = tokens[(size_t)n0 * L + i];
  __syncthreads();
  float4 acc = make_float4(0.f, 0.f, 0.f, 0.f);
  int cnt = 0;
  #pragma unroll
  for (int l = 0; l < L; ++l) {
    int t = toks[r][l];
    float4 v;
    if (TBF) v = b4f(*((const ushort4*)((const unsigned short*)table + (size_t)t * ED + lane * 4)));
    else     v = *(const float4*)((const float*)table + (size_t)t * ED + lane * 4);
    float msk = (t != 0) ? 1.f : 0.f;
    cnt += (t != 0);
    acc.x = fmaf(msk, v.x, acc.x); acc.y = fmaf(msk, v.y, acc.y);
    acc.z = fmaf(msk, v.z, acc.z); acc.w = fmaf(msk, v.w, acc.w);
  }
  float inv = 1.f / (float)(cnt > 0 ? cnt : 1);
  acc.x *= inv; acc.y *= inv; acc.z *= inv; acc.w *= inv;
  if (OUTBF)
    *(ushort4*)((unsigned short*)out + (size_t)(n0 + r) * ED + lane * 4) =
        make_ushort4(bf16_rne(acc.x), bf16_rne(acc.y), bf16_rne(acc.z), bf16_rne(acc.w));
  else
    *(float4*)((float*)out + (size_t)(n0 + r) * ED + lane * 4) = acc;
}

// all three embeddings in one launch: [0,32) desc | [32,1312) x | [1312,11552) mini
__global__ void __launch_bounds__(256)
embed_all_k(const int* __restrict__ desc_tokens, const float* __restrict__ desc_table,
            float* __restrict__ h_n,
            const int* __restrict__ x_tokens, const unsigned short* __restrict__ ctab2,
            float* __restrict__ stmt,
            const int* __restrict__ mini_tokens, const unsigned short* __restrict__ ctab,
            unsigned short* __restrict__ miniE) {
  int b = blockIdx.x;
  if (b < BB / 8) embed_body<LDE, false, false>(desc_tokens, desc_table, h_n, b);
  else if (b < BB / 8 + NO / 8) embed_body<LO, true, false>(x_tokens, ctab2, stmt, b - BB / 8);
  else embed_body<LM, true, true>(mini_tokens, ctab, miniE, b - BB / 8 - NO / 8);
}

// ========== QKVS GEMM v6: single-term (A*Bh), 512 thr = 8 waves x (2m x 4n) tiles =====
// Outputs are bf16-rounded, so the Bl correction term is below output quantization.
// Smaller per-wave tile (acc 32 VGPR) + 8 waves -> 2x latency hiding vs v5.
struct QDesc { const short8* bh; const float* bias; unsigned short* C; };
struct QDesc4 { QDesc d[4]; };

__global__ void __launch_bounds__(512)
mgemm_qkvs6_k(const unsigned short* __restrict__ Ab, QDesc4 g4) {
  const QDesc d = g4.d[blockIdx.x];
  const int n0 = blockIdx.y * 128;
  const int tid = threadIdx.x;
  const int w = tid >> 6, lane = tid & 63;
  const int wm = (w & 3) * 2;        // m-tile base: waves cover mtiles {0..7} in pairs
  const int wn = (w >> 2) * 4;       // n-tile base: {0..3} or {4..7}
  const int r = lane & 15, qd = lane >> 4;
  f32x4 acc[2][4];
  #pragma unroll
  for (int i = 0; i < 2; ++i)
    #pragma unroll
    for (int j = 0; j < 4; ++j) acc[i][j] = (f32x4){0.f, 0.f, 0.f, 0.f};
  #pragma unroll
  for (int kb = 0; kb < 4; ++kb) {
    short8 bh[4];
    #pragma unroll
    for (int j = 0; j < 4; ++j)
      bh[j] = d.bh[((size_t)kb * 8 + wn + j) * 64 + lane];
    short8 a[2];
    #pragma unroll
    for (int i = 0; i < 2; ++i)
      a[i] = *(const short8*)(Ab + (size_t)(n0 + (wm + i) * 16 + r) * ED + kb * 32 + qd * 8);
    #pragma unroll
    for (int i = 0; i < 2; ++i)
      #pragma unroll
      for (int j = 0; j < 4; ++j)
        acc[i][j] = __builtin_amdgcn_mfma_f32_16x16x32_bf16(a[i], bh[j], acc[i][j], 0, 0, 0);
  }
  #pragma unroll
  for (int i = 0; i < 2; ++i)
    #pragma unroll
    for (int j = 0; j < 4; ++j) {
      int col = (wn + j) * 16 + r;
      float bv = d.bias[col];
      #pragma unroll
      for (int rr = 0; rr < 4; ++rr) {
        int row = (wm + i) * 16 + qd * 4 + rr;
        d.C[(size_t)(n0 + row) * ED + col] = bf16_rne(acc[i][j][rr] + bv);
      }
    }
}

// ================= MFMA GEMM (fp32 A, split-bf16 3-term): W2 / W3 path ==============
template<bool RELU>
__global__ void __launch_bounds__(256)
mgemm_k(const float* __restrict__ A, const short8* __restrict__ Bh,
        const short8* __restrict__ Bl, const float* __restrict__ bias,
        float* C, int K, int M) {
  __shared__ short8 Ah[8][64];
  __shared__ short8 Al[8][64];
  const int bm0 = blockIdx.y * 128, bn0 = blockIdx.x * 128;
  const int tid = threadIdx.x;
  const int w = tid >> 6, lane = tid & 63;
  const int wm = (w & 1) * 4, wn = (w >> 1) * 4;
  const int NTm = M / 16;
  f32x4 acc[4][4];
  #pragma unroll
  for (int i = 0; i < 4; ++i)
    #pragma unroll
    for (int j = 0; j < 4; ++j) acc[i][j] = (f32x4){0.f, 0.f, 0.f, 0.f};
  const int kbn = K / 32;
  for (int kb = 0; kb < kbn; ++kb) {
    __syncthreads();
    #pragma unroll
    for (int it = 0; it < 2; ++it) {
      int u = tid + it * 256;
      int mt = u >> 6, l = u & 63;
      int m = bm0 + mt * 16 + (l & 15);
      int k = kb * 32 + ((l >> 4) << 3);
      const float* ap = A + (size_t)m * K + k;
      float4 v0 = *(const float4*)ap;
      float4 v1 = *(const float4*)(ap + 4);
      float f[8] = {v0.x, v0.y, v0.z, v0.w, v1.x, v1.y, v1.z, v1.w};
      short8 hh, ll;
      #pragma unroll
      for (int j = 0; j < 8; ++j) {
        unsigned short hb = bf16_rne(f[j]);
        hh[j] = (short)hb;
        ll[j] = (short)bf16_rne(f[j] - bf16_to_f(hb));
      }
      Ah[mt][l] = hh; Al[mt][l] = ll;
    }
    __syncthreads();
    short8 bh[4], bl[4];
    #pragma unroll
    for (int j = 0; j < 4; ++j) {
      size_t bi = ((size_t)kb * NTm + (bn0 >> 4) + wn + j) * 64 + lane;
      bh[j] = Bh[bi]; bl[j] = Bl[bi];
    }
    #pragma unroll
    for (int i = 0; i < 4; ++i) {
      short8 ah = Ah[wm + i][lane];
      short8 al = Al[wm + i][lane];
      #pragma unroll
      for (int j = 0; j < 4; ++j) {
        acc[i][j] = __builtin_amdgcn_mfma_f32_16x16x32_bf16(ah, bh[j], acc[i][j], 0, 0, 0);
        acc[i][j] = __builtin_amdgcn_mfma_f32_16x16x32_bf16(ah, bl[j], acc[i][j], 0, 0, 0);
        acc[i][j] = __builtin_amdgcn_mfma_f32_16x16x32_bf16(al, bh[j], acc[i][j], 0, 0, 0);
      }
    }
  }
  const int q = lane >> 4, c = lane & 15;
  #pragma unroll
  for (int i = 0; i < 4; ++i)
    #pragma unroll
    for (int j = 0; j < 4; ++j) {
      int col = bn0 + (wn + j) * 16 + c;
      float bv = bias ? bias[col] : 0.f;
      #pragma unroll
      for (int rr = 0; rr < 4; ++rr) {
        int row = bm0 + (wm + i) * 16 + q * 4 + rr;
        float v = acc[i][j][rr] + bv;
        if (RELU) v = fmaxf(v, 0.f);
        C[(size_t)row * M + col] = v;
      }
    }
}

// ================= CSR build (merged scan chain) =================
__global__ void hist2_k(const int* __restrict__ dm, int* __restrict__ hm,
                        const int* __restrict__ dd, int* __restrict__ ho) {
  int e = blockIdx.x * 256 + threadIdx.x;
  if (e < EM) atomicAdd(&hm[dm[e]], 1);
  else { int e2 = e - EM; if (e2 < EO) atomicAdd(&ho[dd[e2]], 1); }
}
__global__ void chunk_sum_k(const int* __restrict__ hist, int* __restrict__ partials, int N) {
  __shared__ int sd[256];
  int i = blockIdx.x * 256 + threadIdx.x;
  sd[threadIdx.x] = (i < N) ? hist[i] : 0;
  __syncthreads();
  for (int s = 128; s > 0; s >>= 1) {
    if (threadIdx.x < s) sd[threadIdx.x] += sd[threadIdx.x + s];
    __syncthreads();
  }
  if (threadIdx.x == 0) partials[blockIdx.x] = sd[0];
}
__global__ void scan_partials2_k(int* __restrict__ p) {
  __shared__ int sd[512];
  int base = (blockIdx.x == 0) ? 0 : NM / 256;
  int B    = (blockIdx.x == 0) ? NM / 256 : NO / 256;
  int t = threadIdx.x;
  int v = (t < B) ? p[base + t] : 0;
  sd[t] = v; __syncthreads();
  for (int off = 1; off < 512; off <<= 1) {
    int a = (t >= off) ? sd[t - off] : 0;
    __syncthreads();
    sd[t] += a;
    __syncthreads();
  }
  if (t < B) p[base + t] = sd[t] - v;   // exclusive
}
__global__ void scan_final2_k(const int* __restrict__ hist, const int* __restrict__ partials,
                              int* __restrict__ offsm, int* __restrict__ curm,
                              int* __restrict__ offso, int* __restrict__ curo,
                              float* __restrict__ dinv) {
  __shared__ int sd[256];
  int i = blockIdx.x * 256 + threadIdx.x;
  int v = hist[i];
  sd[threadIdx.x] = v; __syncthreads();
  for (int off = 1; off < 256; off <<= 1) {
    int a = (threadIdx.x >= off) ? sd[threadIdx.x - off] : 0;
    __syncthreads();
    sd[threadIdx.x] += a;
    __syncthreads();
  }
  int excl = sd[threadIdx.x] - v + partials[blockIdx.x];
  if (i < NM) {
    offsm[i] = excl; curm[i] = excl;
    if (i == NM - 1) offsm[NM] = excl + v;
  } else {
    int i2 = i - NM;
    offso[i2] = excl; curo[i2] = excl;
    if (i2 == NO - 1) offso[NO] = excl + v;
    dinv[i2] = 1.f / sqrtf(1.f + (float)v);
  }
}
__global__ void scatter2_k(const int* __restrict__ sm, const int* __restrict__ dm,
                           int* __restrict__ cm, int* __restrict__ km,
                           const int* __restrict__ so, const int* __restrict__ dd,
                           int* __restrict__ co, int* __restrict__ ko) {
  int e = blockIdx.x * 256 + threadIdx.x;
  if (e < EM) {
    int pos = atomicAdd(&cm[dm[e]], 1);
    km[pos] = sm[e];
  } else {
    int e2 = e - EM;
    if (e2 < EO) {
      int pos = atomicAdd(&co[dd[e2]], 1);
      ko[pos] = so[e2];
    }
  }
}

// ============ fused TransformerConv (bf16 streams): flash per dst + skip + gate ======
__global__ void __launch_bounds__(128)
attn_fused_k(unsigned short* qh, const unsigned short* __restrict__ kk,
             const unsigned short* __restrict__ vv, const unsigned short* __restrict__ skip,
             const int* __restrict__ offs, const int* __restrict__ csr,
             const float* __restrict__ Wg, const float* __restrict__ bg,
             float* __restrict__ gateOut) {
  const int g = threadIdx.x >> 5, lane = threadIdx.x & 31;
  const int n = blockIdx.x * 4 + g;
  float4 q = b4f(*(const ushort4*)(qh + (size_t)n * ED + lane * 4));
  int lo = offs[n], hi = offs[n + 1];
  float4 O = make_float4(0.f, 0.f, 0.f, 0.f);
  float m = -INFINITY, l = 0.f;
  for (int e = lo; e < hi; ++e) {
    int s = csr[e];
    float4 kt = b4f(*(const ushort4*)(kk + (size_t)s * ED + lane * 4));
    float4 vt = b4f(*(const ushort4*)(vv + (size_t)s * ED + lane * 4));
    float p = q.x * kt.x + q.y * kt.y + q.z * kt.z + q.w * kt.w;
    p += __shfl_xor(p, 1, 64);
    p += __shfl_xor(p, 2, 64);
    float sc = p * 0.25f;               // 1/sqrt(Dh)
    float mn = fmaxf(m, sc);
    float scale = __expf(m - mn);       // exp(-inf)=0 handles first edge
    float pe = __expf(sc - mn);
    l = l * scale + pe;
    O.x = O.x * scale + pe * vt.x; O.y = O.y * scale + pe * vt.y;
    O.z = O.z * scale + pe * vt.z; O.w = O.w * scale + pe * vt.w;
    m = mn;
  }
  float inv = 1.f / (l + 1e-16f);
  float4 sk = b4f(*(const ushort4*)(skip + (size_t)n * ED + lane * 4));
  float4 out = make_float4(O.x * inv + sk.x, O.y * inv + sk.y,
                           O.z * inv + sk.z, O.w * inv + sk.w);
  *(ushort4*)(qh + (size_t)n * ED + lane * 4) =
      make_ushort4(bf16_rne(out.x), bf16_rne(out.y), bf16_rne(out.z), bf16_rne(out.w));
  float4 wg = *(const float4*)(Wg + lane * 4);
  float ps = out.x * wg.x + out.y * wg.y + out.z * wg.z + out.w * wg.w;
  #pragma unroll
  for (int o = 1; o <= 16; o <<= 1) ps += __shfl_xor(ps, o, 64);
  if (lane == 0) gateOut[n] = ps + bg[0];
}

// ============ GCN gather (fp32): 4 nodes x 32 float4-lanes ============
__global__ void __launch_bounds__(128)
gcn_gather_k(const float* __restrict__ x, const float* __restrict__ dinv,
             const int* __restrict__ offs, const int* __restrict__ csr,
             const float* __restrict__ bias, float* __restrict__ out,
             const float* __restrict__ Wg, const float* __restrict__ bg,
             float* __restrict__ gateOut) {
  const int g = threadIdx.x >> 5, lane = threadIdx.x & 31;
  const int n = blockIdx.x * 4 + g;
  float di = dinv[n];
  float4 xs = *(const float4*)(x + (size_t)n * ED + lane * 4);
  float w0 = di * di;
  float4 acc = make_float4(w0 * xs.x, w0 * xs.y, w0 * xs.z, w0 * xs.w);
  int lo = offs[n], hi = offs[n + 1];
  for (int e = lo; e < hi; ++e) {
    int s = csr[e];
    float w = di * dinv[s];
    float4 v = *(const float4*)(x + (size_t)s * ED + lane * 4);
    acc.x = fmaf(w, v.x, acc.x); acc.y = fmaf(w, v.y, acc.y);
    acc.z = fmaf(w, v.z, acc.z); acc.w = fmaf(w, v.w, acc.w);
  }
  if (bias) {
    float4 b4 = *(const float4*)(bias + lane * 4);
    acc.x += b4.x; acc.y += b4.y; acc.z += b4.z; acc.w += b4.w;
  }
  *(float4*)(out + (size_t)n * ED + lane * 4) = acc;
  if (gateOut) {
    float4 wg = *(const float4*)(Wg + lane * 4);
    float ps = acc.x * wg.x + acc.y * wg.y + acc.z * wg.z + acc.w * wg.w;
    #pragma unroll
    for (int o = 1; o <= 16; o <<= 1) ps += __shfl_xor(ps, o, 64);
    if (lane == 0) gateOut[n] = ps + bg[0];
  }
}

// ============ global attention over contiguous (sorted) segments ============
static __device__ __forceinline__ int lower_bound_d(const int* a, int n, int key) {
  int lo = 0, hi = n;
  while (lo < hi) { int mid = (lo + hi) >> 1; if (a[mid] < key) lo = mid + 1; else hi = mid; }
  return lo;
}
template<bool COMBINE, bool XBF>
__global__ void __launch_bounds__(128)
gattn_k(const void* __restrict__ xv, const float* __restrict__ gate,
        const int* __restrict__ seg, int Ntot,
        const float* __restrict__ other, float* __restrict__ out) {
  const int g = threadIdx.x >> 5, lane = threadIdx.x & 31;
  const int n = blockIdx.x * 4 + g;
  __shared__ int sh[4][2];
  if (lane == 0) {
    sh[g][0] = lower_bound_d(seg, Ntot, n);
    sh[g][1] = lower_bound_d(seg, Ntot, n + 1);
  }
  __syncthreads();
  int lo = sh[g][0], hi = sh[g][1];
  float m = -INFINITY;
  for (int j = lo; j < hi; ++j) m = fmaxf(m, gate[j]);
  float ssum = 0.f;
  for (int j = lo; j < hi; ++j) ssum += __expf(gate[j] - m);
  float inv = 1.f / (ssum + 1e-16f);
  float4 acc = make_float4(0.f, 0.f, 0.f, 0.f);
  for (int j = lo; j < hi; ++j) {
    float a = __expf(gate[j] - m) * inv;
    float4 v;
    if (XBF) v = b4f(*((const ushort4*)((const unsigned short*)xv + (size_t)j * ED + lane * 4)));
    else     v = *((const float4*)((const float*)xv + (size_t)j * ED) + lane);
    acc.x = fmaf(a, v.x, acc.x); acc.y = fmaf(a, v.y, acc.y);
    acc.z = fmaf(a, v.z, acc.z); acc.w = fmaf(a, v.w, acc.w);
  }
  if (COMBINE) {
    float4 o4 = *(const float4*)(other + (size_t)n * ED + lane * 4);
    acc.x = (acc.x + o4.x) * 0.5f; acc.y = (acc.y + o4.y) * 0.5f;
    acc.z = (acc.z + o4.z) * 0.5f; acc.w = (acc.w + o4.w) * 0.5f;
  }
  *(float4*)(out + (size_t)n * ED + lane * 4) = acc;
}

// ============ final global attention NO->BB with cosine fused ====
__global__ void __launch_bounds__(128)
gattn_cos_k(const float* __restrict__ x, const float* __restrict__ gate,
            const int* __restrict__ seg, int Ntot,
            const float* __restrict__ hn, float* __restrict__ outp) {
  const int g = threadIdx.x >> 5, lane = threadIdx.x & 31;
  const int n = blockIdx.x * 4 + g;
  __shared__ int sh[4][2];
  if (lane == 0) {
    sh[g][0] = lower_bound_d(seg, Ntot, n);
    sh[g][1] = lower_bound_d(seg, Ntot, n + 1);
  }
  __syncthreads();
  int lo = sh[g][0], hi = sh[g][1];
  float m = -INFINITY;
  for (int j = lo; j < hi; ++j) m = fmaxf(m, gate[j]);
  float ssum = 0.f;
  for (int j = lo; j < hi; ++j) ssum += __expf(gate[j] - m);
  float inv = 1.f / (ssum + 1e-16f);
  float4 acc = make_float4(0.f, 0.f, 0.f, 0.f);
  for (int j = lo; j < hi; ++j) {
    float a = __expf(gate[j] - m) * inv;
    float4 v = *((const float4*)(x + (size_t)j * ED) + lane);
    acc.x = fmaf(a, v.x, acc.x); acc.y = fmaf(a, v.y, acc.y);
    acc.z = fmaf(a, v.z, acc.z); acc.w = fmaf(a, v.w, acc.w);
  }
  float4 hv = *(const float4*)(hn + (size_t)n * ED + lane * 4);
  float dot = acc.x * hv.x + acc.y * hv.y + acc.z * hv.z + acc.w * hv.w;
  float na  = acc.x * acc.x + acc.y * acc.y + acc.z * acc.z + acc.w * acc.w;
  float nb  = hv.x * hv.x + hv.y * hv.y + hv.z * hv.z + hv.w * hv.w;
  #pragma unroll
  for (int o = 1; o <= 16; o <<= 1) {
    dot += __shfl_xor(dot, o, 64);
    na  += __shfl_xor(na,  o, 64);
    nb  += __shfl_xor(nb,  o, 64);
  }
  if (lane == 0)
    outp[n] = dot / (fmaxf(sqrtf(na), 1e-8f) * fmaxf(sqrtf(nb), 1e-8f));
}

// ---- workspace layout (4-byte element offsets) ----
constexpr size_t OFF_HN    = 0;                                  // BB*ED
constexpr size_t OFF_STMT  = OFF_HN    + (size_t)BB * ED;        // NO*ED
constexpr size_t OFF_A     = OFF_STMT  + (size_t)NO * ED;        // NM*ED (miniE bf16 -> recycled)
constexpr size_t OFF_QHID  = OFF_A     + (size_t)NM * ED;        // NM*ED floats (bf16 q->hid in 1st half)
constexpr size_t OFF_CT    = OFF_QHID  + (size_t)NM * ED / 2;    // 2nd half of QHID: bf16 tables
constexpr size_t OFF_K     = OFF_QHID  + (size_t)NM * ED;        // NM*ED floats (bf16 k + bf16 skip)
constexpr size_t OFF_V     = OFF_K     + (size_t)NM * ED;        // NM*ED floats (bf16 v in 1st half)
constexpr size_t T0        = OFF_V     + (size_t)NM * ED;
constexpr size_t OFF_GATE  = T0;                                 // NM
constexpr size_t OFF_GATE2 = OFF_GATE  + (size_t)NM;             // NO
constexpr size_t OFF_DINV  = OFF_GATE2 + (size_t)NO;             // NO
constexpr size_t OFF_HISTM = OFF_DINV  + (size_t)NO;             // NM (int)
constexpr size_t OFF_HISTO = OFF_HISTM + (size_t)NM;             // NO (adjacent -> concat scan)
constexpr size_t OFF_OFFSM = OFF_HISTO + (size_t)NO;             // NM+1
constexpr size_t OFF_CURM  = OFF_OFFSM + (size_t)NM + 1;         // NM
constexpr size_t OFF_CSRM  = OFF_CURM  + (size_t)NM;             // EM
constexpr size_t OFF_OFFSO = OFF_CSRM  + (size_t)EM;             // NO+1
constexpr size_t OFF_CURO  = OFF_OFFSO + (size_t)NO + 1;         // NO
constexpr size_t OFF_CSRO  = OFF_CURO  + (size_t)NO;             // EO
constexpr size_t OFF_PART  = OFF_CSRO  + (size_t)EO;             // 512 (int)
constexpr size_t OFF_WFHI  = OFF_PART  + 512;                    // 65536 floats
constexpr size_t OFF_WFLO  = OFF_WFHI  + 65536;                  // 65536 floats
constexpr size_t WO_Q  = 0, WO_K = 2048, WO_V = 4096, WO_S = 6144, WO_W2 = 8192, WO_W3 = 12288;
// region-A recycling after attn (miniE dead):
constexpr size_t OFF_MFN   = OFF_A;                              // NO*ED
constexpr size_t OFF_AGG   = OFF_MFN   + (size_t)NO * ED;        // NO*ED
constexpr size_t OFF_H     = OFF_AGG   + (size_t)NO * ED;        // NO*HIDD
constexpr size_t OFF_T     = OFF_H     + (size_t)NO * HIDD;      // NO*ED
constexpr size_t OFF_FIN   = OFF_T     + (size_t)NO * ED;        // NO*ED

extern "C" void kernel_launch(void* const* d_in, const int* in_sizes, int n_in,
                              void* d_out, int out_size, void* d_ws, size_t ws_size,
                              hipStream_t stream) {
  const int* desc_tokens = (const int*)d_in[0];
  const int* x_tokens    = (const int*)d_in[1];
  const int* mini_tokens = (const int*)d_in[2];
  const int* src         = (const int*)d_in[3];
  const int* dst         = (const int*)d_in[4];
  const int* mini_src    = (const int*)d_in[5];
  const int* mini_dst    = (const int*)d_in[6];
  const int* mini_batch  = (const int*)d_in[7];
  const int* node_batch  = (const int*)d_in[8];
  const float* desc_table  = (const float*)d_in[9];
  const float* code_table  = (const float*)d_in[10];
  const float* code_table2 = (const float*)d_in[11];
  const float* Wq = (const float*)d_in[12]; const float* bq = (const float*)d_in[13];
  const float* Wk = (const float*)d_in[14]; const float* bk = (const float*)d_in[15];
  const float* Wv = (const float*)d_in[16]; const float* bv = (const float*)d_in[17];
  const float* Wskip = (const float*)d_in[18]; const float* bskip = (const float*)d_in[19];
  const float* W2 = (const float*)d_in[20]; const float* b2 = (const float*)d_in[21];
  const float* W3 = (const float*)d_in[22]; const float* b3 = (const float*)d_in[23];
  const float* Wg = (const float*)d_in[24]; const float* bg = (const float*)d_in[25];

  float* ws = (float*)d_ws;
  float* h_n   = ws + OFF_HN;
  float* stmt  = ws + OFF_STMT;
  unsigned short* miniE_b = (unsigned short*)(ws + OFF_A);    // bf16 [NM][128]
  unsigned short* qhid_b = (unsigned short*)(ws + OFF_QHID);  // q -> hid, bf16
  unsigned short* ctab_b  = (unsigned short*)(ws + OFF_CT);             // bf16 code_table
  unsigned short* ctab2_b = (unsigned short*)(ws + OFF_CT + (size_t)VV * ED / 2);
  unsigned short* kbuf_b = (unsigned short*)(ws + OFF_K);     // k, bf16
  unsigned short* skip_b = kbuf_b + (size_t)NM * ED;          // skip, bf16 (2nd half)
  unsigned short* vbuf_b = (unsigned short*)(ws + OFF_V);     // v, bf16
  float* gate  = ws + OFF_GATE;
  float* gate2 = ws + OFF_GATE2;
  float* dinv  = ws + OFF_DINV;
  int* histm = (int*)(ws + OFF_HISTM);
  int* histo = (int*)(ws + OFF_HISTO);
  int* offsm = (int*)(ws + OFF_OFFSM);
  int* curm  = (int*)(ws + OFF_CURM);
  int* csrm  = (int*)(ws + OFF_CSRM);
  int* offso = (int*)(ws + OFF_OFFSO);
  int* curo  = (int*)(ws + OFF_CURO);
  int* csro  = (int*)(ws + OFF_CSRO);
  int* part  = (int*)(ws + OFF_PART);
  short8* wfhi = (short8*)(ws + OFF_WFHI);
  short8* wflo = (short8*)(ws + OFF_WFLO);
  float* mini_fn = ws + OFF_MFN;
  float* aggb    = ws + OFF_AGG;
  float* hbuf    = ws + OFF_H;
  float* tbuf    = ws + OFF_T;
  float* finalS  = ws + OFF_FIN;
  float* outp    = (float*)d_out;

  // ---- all conversions in ONE launch: 6 weights + 2 tables ----
  WC6 wc;
  wc.w[0] = {Wq,    ED,   ED,   wfhi + WO_Q,  wflo + WO_Q,  (int)WO_Q};
  wc.w[1] = {Wk,    ED,   ED,   wfhi + WO_K,  wflo + WO_K,  (int)WO_K};
  wc.w[2] = {Wv,    ED,   ED,   wfhi + WO_V,  wflo + WO_V,  (int)WO_V};
  wc.w[3] = {Wskip, ED,   ED,   wfhi + WO_S,  wflo + WO_S,  (int)WO_S};
  wc.w[4] = {W2,    ED,   HIDD, wfhi + WO_W2, wflo + WO_W2, (int)WO_W2};
  wc.w[5] = {W3,    HIDD, ED,   wfhi + WO_W3, wflo + WO_W3, (int)WO_W3};
  conv_all_k<<<64 + nblk(2 * VV * ED / 4, 256), 256, 0, stream>>>(
      wc, code_table, ctab_b, code_table2, ctab2_b);

  // ---- CSR build: merged hist/scatter + single concat scan chain + fused dinv ----
  hipMemsetAsync(histm, 0, (size_t)(NM + NO) * 4, stream);
  hist2_k<<<nblk(EM + EO, 256), 256, 0, stream>>>(mini_dst, histm, dst, histo);
  chunk_sum_k<<<(NM + NO) / 256, 256, 0, stream>>>(histm, part, NM + NO);
  scan_partials2_k<<<2, 512, 0, stream>>>(part);
  scan_final2_k<<<(NM + NO) / 256, 256, 0, stream>>>(histm, part, offsm, curm,
                                                     offso, curo, dinv);
  scatter2_k<<<nblk(EM + EO, 256), 256, 0, stream>>>(mini_src, mini_dst, curm, csrm,
                                                     src, dst, curo, csro);

  // ---- all three embeddings in one launch ----
  embed_all_k<<<BB / 8 + NO / 8 + NM / 8, 256, 0, stream>>>(
      desc_tokens, desc_table, h_n, x_tokens, ctab2_b, stmt,
      mini_tokens, ctab_b, miniE_b);

  // ---- Q,K,V,Skip projections: single-term bf16 MFMA, 8 waves/block ----
  QDesc4 g4;
  g4.d[0] = {wfhi + WO_Q, bq,    qhid_b};
  g4.d[1] = {wfhi + WO_K, bk,    kbuf_b};
  g4.d[2] = {wfhi + WO_V, bv,    vbuf_b};
  g4.d[3] = {wfhi + WO_S, bskip, skip_b};
  { dim3 g(4, NM / 128); mgemm_qkvs6_k<<<g, 512, 0, stream>>>(miniE_b, g4); }

  // ---- fused transformer conv (flash per dst, bf16 streams) + gate ----
  attn_fused_k<<<NM / 4, 128, 0, stream>>>(qhid_b, kbuf_b, vbuf_b, skip_b,
                                           offsm, csrm, Wg, bg, gate);

  // ---- global attention mini -> NO, fused with (x + stmt)*0.5 ----
  gattn_k<true, true><<<NO / 4, 128, 0, stream>>>(qhid_b, gate, mini_batch, NM, stmt, mini_fn);

  // ---- GCN conv 1: agg = A_hat * mini_fn ; h = relu(agg @ W2 + b2) ----
  gcn_gather_k<<<NO / 4, 128, 0, stream>>>(mini_fn, dinv, offso, csro, nullptr, aggb,
                                           nullptr, nullptr, nullptr);
  { dim3 g(HIDD / 128, NO / 128);
    mgemm_k<true><<<g, 256, 0, stream>>>(aggb, wfhi + WO_W2, wflo + WO_W2, b2, hbuf, ED, HIDD); }

  // ---- GCN conv 2: t = h @ W3 ; final = A_hat * t + b3 (+ fused gate2) ----
  { dim3 g(1, NO / 128);
    mgemm_k<false><<<g, 256, 0, stream>>>(hbuf, wfhi + WO_W3, wflo + WO_W3, nullptr, tbuf, HIDD, ED); }
  gcn_gather_k<<<NO / 4, 128, 0, stream>>>(tbuf, dinv, offso, csro, b3, finalS, Wg, bg, gate2);

  // ---- global attention NO -> BB with fused cosine -> d_out [BB] ----
  gattn_cos_k<<<BB / 4, 128, 0, stream>>>(finalS, gate2, node_batch, NO, h_n, outp);
}

// Round 12
// 367.127 us; speedup vs baseline: 1.0530x; 1.0136x over previous
//
#include <hip/hip_runtime.h>
#include <hip/hip_bf16.h>
#include <math.h>

// Problem dims (fixed by reference)
#define BB   256      // batch
#define LDE  64       // desc tokens len
#define NO   10240    // outer nodes
#define LO   32       // x tokens len
#define NM   81920    // mini nodes
#define LM   16       // mini tokens len
#define EO   81920    // outer edges
#define EM   327680   // mini edges
#define ED   128      // embed dim E
#define HIDD 256      // hidden
#define NH   8        // heads
#define DH   16       // head dim
#define VV   10000    // vocab

static inline int nblk(long long n, int b) { return (int)((n + b - 1) / b); }

typedef __attribute__((ext_vector_type(8))) short short8;
typedef __attribute__((ext_vector_type(4))) float f32x4;

// ---- fp32 <-> bf16 (RNE) helpers ----
static __device__ __forceinline__ unsigned short bf16_rne(float f) {
  unsigned u = __float_as_uint(f);
  return (unsigned short)((u + 0x7fffu + ((u >> 16) & 1u)) >> 16);
}
static __device__ __forceinline__ float bf16_to_f(unsigned short h) {
  return __uint_as_float(((unsigned)h) << 16);
}
static __device__ __forceinline__ float4 b4f(ushort4 h) {
  return make_float4(bf16_to_f(h.x), bf16_to_f(h.y), bf16_to_f(h.z), bf16_to_f(h.w));
}

// ============ merged conversion kernel: 6 weights -> split-bf16 frags, 2 tables -> bf16
struct WC { const float* W; int K, M; short8* hi; short8* lo; int base; };
struct WC6 { WC w[6]; };
__global__ void __launch_bounds__(256)
conv_all_k(WC6 wc, const float* __restrict__ t1, unsigned short* __restrict__ o1,
           const float* __restrict__ t2, unsigned short* __restrict__ o2) {
  if (blockIdx.x < 64) {
    int g = blockIdx.x * 256 + threadIdx.x;   // octet id, 0..16383
    int wi = 0;
    #pragma unroll
    for (int i = 1; i < 6; ++i) if (g >= wc.w[i].base) wi = i;
    const WC c = wc.w[wi];
    int idx = g - c.base;
    int lane = idx & 63;
    int nt = (idx >> 6) % (c.M / 16);
    int kb = (idx >> 6) / (c.M / 16);
    int n = nt * 16 + (lane & 15);
    int k0 = kb * 32 + ((lane >> 4) << 3);
    short8 h, l;
    #pragma unroll
    for (int j = 0; j < 8; ++j) {
      float v = c.W[(size_t)(k0 + j) * c.M + n];
      unsigned short hb = bf16_rne(v);
      h[j] = (short)hb;
      l[j] = (short)bf16_rne(v - bf16_to_f(hb));
    }
    c.hi[idx] = h; c.lo[idx] = l;
  } else {
    int q = (blockIdx.x - 64) * 256 + threadIdx.x;   // quad id
    const int NT = VV * ED / 4;                       // 320000 per table
    if (q < NT) {
      float4 v = *(const float4*)(t1 + (size_t)q * 4);
      *(ushort4*)(o1 + (size_t)q * 4) =
          make_ushort4(bf16_rne(v.x), bf16_rne(v.y), bf16_rne(v.z), bf16_rne(v.w));
    } else if (q < 2 * NT) {
      int q2 = q - NT;
      float4 v = *(const float4*)(t2 + (size_t)q2 * 4);
      *(ushort4*)(o2 + (size_t)q2 * 4) =
          make_ushort4(bf16_rne(v.x), bf16_rne(v.y), bf16_rne(v.z), bf16_rne(v.w));
    }
  }
}

// ---- embedding masked mean body: 256 thr = 8 rows x 32 4-elem lanes ----
template<int L, bool TBF, bool OUTBF>
static __device__ __forceinline__ void embed_body(const int* __restrict__ tokens,
                                                  const void* __restrict__ table,
                                                  void* __restrict__ out, int blk) {
  const int r = threadIdx.x >> 5, lane = threadIdx.x & 31;
  const int n0 = blk * 8;
  __shared__ int toks[8][L];
  for (int i = threadIdx.x; i < 8 * L; i += 256)
    toks[i / L][i % L] = tokens[(size_t)n0 * L + i];
  __syncthreads();
  float4 acc = make_float4(0.f, 0.f, 0.f, 0.f);
  int cnt = 0;
  #pragma unroll
  for (int l = 0; l < L; ++l) {
    int t = toks[r][l];
    float4 v;
    if (TBF) v = b4f(*((const ushort4*)((const unsigned short*)table + (size_t)t * ED + lane * 4)));
    else     v = *(const float4*)((const float*)table + (size_t)t * ED + lane * 4);
    float msk = (t != 0) ? 1.f : 0.f;
    cnt += (t != 0);
    acc.x = fmaf(msk, v.x, acc.x); acc.y = fmaf(msk, v.y, acc.y);
    acc.z = fmaf(msk, v.z, acc.z); acc.w = fmaf(msk, v.w, acc.w);
  }
  float inv = 1.f / (float)(cnt > 0 ? cnt : 1);
  acc.x *= inv; acc.y *= inv; acc.z *= inv; acc.w *= inv;
  if (OUTBF)
    *(ushort4*)((unsigned short*)out + (size_t)(n0 + r) * ED + lane * 4) =
        make_ushort4(bf16_rne(acc.x), bf16_rne(acc.y), bf16_rne(acc.z), bf16_rne(acc.w));
  else
    *(float4*)((float*)out + (size_t)(n0 + r) * ED + lane * 4) = acc;
}

// all three embeddings in one launch: [0,32) desc | [32,1312) x | [1312,11552) mini
__global__ void __launch_bounds__(256)
embed_all_k(const int* __restrict__ desc_tokens, const float* __restrict__ desc_table,
            float* __restrict__ h_n,
            const int* __restrict__ x_tokens, const unsigned short* __restrict__ ctab2,
            float* __restrict__ stmt,
            const int* __restrict__ mini_tokens, const unsigned short* __restrict__ ctab,
            unsigned short* __restrict__ miniE) {
  int b = blockIdx.x;
  if (b < BB / 8) embed_body<LDE, false, false>(desc_tokens, desc_table, h_n, b);
  else if (b < BB / 8 + NO / 8) embed_body<LO, true, false>(x_tokens, ctab2, stmt, b - BB / 8);
  else embed_body<LM, true, true>(mini_tokens, ctab, miniE, b - BB / 8 - NO / 8);
}

// ========== QKVS GEMM v6: single-term (A*Bh), 512 thr = 8 waves x (2m x 4n) tiles =====
struct QDesc { const short8* bh; const float* bias; unsigned short* C; };
struct QDesc4 { QDesc d[4]; };

__global__ void __launch_bounds__(512)
mgemm_qkvs6_k(const unsigned short* __restrict__ Ab, QDesc4 g4) {
  const QDesc d = g4.d[blockIdx.x];
  const int n0 = blockIdx.y * 128;
  const int tid = threadIdx.x;
  const int w = tid >> 6, lane = tid & 63;
  const int wm = (w & 3) * 2;        // m-tile base
  const int wn = (w >> 2) * 4;       // n-tile base
  const int r = lane & 15, qd = lane >> 4;
  f32x4 acc[2][4];
  #pragma unroll
  for (int i = 0; i < 2; ++i)
    #pragma unroll
    for (int j = 0; j < 4; ++j) acc[i][j] = (f32x4){0.f, 0.f, 0.f, 0.f};
  #pragma unroll
  for (int kb = 0; kb < 4; ++kb) {
    short8 bh[4];
    #pragma unroll
    for (int j = 0; j < 4; ++j)
      bh[j] = d.bh[((size_t)kb * 8 + wn + j) * 64 + lane];
    short8 a[2];
    #pragma unroll
    for (int i = 0; i < 2; ++i)
      a[i] = *(const short8*)(Ab + (size_t)(n0 + (wm + i) * 16 + r) * ED + kb * 32 + qd * 8);
    #pragma unroll
    for (int i = 0; i < 2; ++i)
      #pragma unroll
      for (int j = 0; j < 4; ++j)
        acc[i][j] = __builtin_amdgcn_mfma_f32_16x16x32_bf16(a[i], bh[j], acc[i][j], 0, 0, 0);
  }
  #pragma unroll
  for (int i = 0; i < 2; ++i)
    #pragma unroll
    for (int j = 0; j < 4; ++j) {
      int col = (wn + j) * 16 + r;
      float bv = d.bias[col];
      #pragma unroll
      for (int rr = 0; rr < 4; ++rr) {
        int row = (wm + i) * 16 + qd * 4 + rr;
        d.C[(size_t)(n0 + row) * ED + col] = bf16_rne(acc[i][j][rr] + bv);
      }
    }
}

// ================= MFMA GEMM (fp32 A, split-bf16 3-term): W2 / W3 path ==============
template<bool RELU>
__global__ void __launch_bounds__(256)
mgemm_k(const float* __restrict__ A, const short8* __restrict__ Bh,
        const short8* __restrict__ Bl, const float* __restrict__ bias,
        float* C, int K, int M) {
  __shared__ short8 Ah[8][64];
  __shared__ short8 Al[8][64];
  const int bm0 = blockIdx.y * 128, bn0 = blockIdx.x * 128;
  const int tid = threadIdx.x;
  const int w = tid >> 6, lane = tid & 63;
  const int wm = (w & 1) * 4, wn = (w >> 1) * 4;
  const int NTm = M / 16;
  f32x4 acc[4][4];
  #pragma unroll
  for (int i = 0; i < 4; ++i)
    #pragma unroll
    for (int j = 0; j < 4; ++j) acc[i][j] = (f32x4){0.f, 0.f, 0.f, 0.f};
  const int kbn = K / 32;
  for (int kb = 0; kb < kbn; ++kb) {
    __syncthreads();
    #pragma unroll
    for (int it = 0; it < 2; ++it) {
      int u = tid + it * 256;
      int mt = u >> 6, l = u & 63;
      int m = bm0 + mt * 16 + (l & 15);
      int k = kb * 32 + ((l >> 4) << 3);
      const float* ap = A + (size_t)m * K + k;
      float4 v0 = *(const float4*)ap;
      float4 v1 = *(const float4*)(ap + 4);
      float f[8] = {v0.x, v0.y, v0.z, v0.w, v1.x, v1.y, v1.z, v1.w};
      short8 hh, ll;
      #pragma unroll
      for (int j = 0; j < 8; ++j) {
        unsigned short hb = bf16_rne(f[j]);
        hh[j] = (short)hb;
        ll[j] = (short)bf16_rne(f[j] - bf16_to_f(hb));
      }
      Ah[mt][l] = hh; Al[mt][l] = ll;
    }
    __syncthreads();
    short8 bh[4], bl[4];
    #pragma unroll
    for (int j = 0; j < 4; ++j) {
      size_t bi = ((size_t)kb * NTm + (bn0 >> 4) + wn + j) * 64 + lane;
      bh[j] = Bh[bi]; bl[j] = Bl[bi];
    }
    #pragma unroll
    for (int i = 0; i < 4; ++i) {
      short8 ah = Ah[wm + i][lane];
      short8 al = Al[wm + i][lane];
      #pragma unroll
      for (int j = 0; j < 4; ++j) {
        acc[i][j] = __builtin_amdgcn_mfma_f32_16x16x32_bf16(ah, bh[j], acc[i][j], 0, 0, 0);
        acc[i][j] = __builtin_amdgcn_mfma_f32_16x16x32_bf16(ah, bl[j], acc[i][j], 0, 0, 0);
        acc[i][j] = __builtin_amdgcn_mfma_f32_16x16x32_bf16(al, bh[j], acc[i][j], 0, 0, 0);
      }
    }
  }
  const int q = lane >> 4, c = lane & 15;
  #pragma unroll
  for (int i = 0; i < 4; ++i)
    #pragma unroll
    for (int j = 0; j < 4; ++j) {
      int col = bn0 + (wn + j) * 16 + c;
      float bv = bias ? bias[col] : 0.f;
      #pragma unroll
      for (int rr = 0; rr < 4; ++rr) {
        int row = bm0 + (wm + i) * 16 + q * 4 + rr;
        float v = acc[i][j][rr] + bv;
        if (RELU) v = fmaxf(v, 0.f);
        C[(size_t)row * M + col] = v;
      }
    }
}

// ================= CSR build (merged scan chain) =================
__global__ void hist2_k(const int* __restrict__ dm, int* __restrict__ hm,
                        const int* __restrict__ dd, int* __restrict__ ho) {
  int e = blockIdx.x * 256 + threadIdx.x;
  if (e < EM) atomicAdd(&hm[dm[e]], 1);
  else { int e2 = e - EM; if (e2 < EO) atomicAdd(&ho[dd[e2]], 1); }
}
__global__ void chunk_sum_k(const int* __restrict__ hist, int* __restrict__ partials, int N) {
  __shared__ int sd[256];
  int i = blockIdx.x * 256 + threadIdx.x;
  sd[threadIdx.x] = (i < N) ? hist[i] : 0;
  __syncthreads();
  for (int s = 128; s > 0; s >>= 1) {
    if (threadIdx.x < s) sd[threadIdx.x] += sd[threadIdx.x + s];
    __syncthreads();
  }
  if (threadIdx.x == 0) partials[blockIdx.x] = sd[0];
}
__global__ void scan_partials2_k(int* __restrict__ p) {
  __shared__ int sd[512];
  int base = (blockIdx.x == 0) ? 0 : NM / 256;
  int B    = (blockIdx.x == 0) ? NM / 256 : NO / 256;
  int t = threadIdx.x;
  int v = (t < B) ? p[base + t] : 0;
  sd[t] = v; __syncthreads();
  for (int off = 1; off < 512; off <<= 1) {
    int a = (t >= off) ? sd[t - off] : 0;
    __syncthreads();
    sd[t] += a;
    __syncthreads();
  }
  if (t < B) p[base + t] = sd[t] - v;   // exclusive
}
__global__ void scan_final2_k(const int* __restrict__ hist, const int* __restrict__ partials,
                              int* __restrict__ offsm, int* __restrict__ curm,
                              int* __restrict__ offso, int* __restrict__ curo,
                              float* __restrict__ dinv) {
  __shared__ int sd[256];
  int i = blockIdx.x * 256 + threadIdx.x;
  int v = hist[i];
  sd[threadIdx.x] = v; __syncthreads();
  for (int off = 1; off < 256; off <<= 1) {
    int a = (threadIdx.x >= off) ? sd[threadIdx.x - off] : 0;
    __syncthreads();
    sd[threadIdx.x] += a;
    __syncthreads();
  }
  int excl = sd[threadIdx.x] - v + partials[blockIdx.x];
  if (i < NM) {
    offsm[i] = excl; curm[i] = excl;
    if (i == NM - 1) offsm[NM] = excl + v;
  } else {
    int i2 = i - NM;
    offso[i2] = excl; curo[i2] = excl;
    if (i2 == NO - 1) offso[NO] = excl + v;
    dinv[i2] = 1.f / sqrtf(1.f + (float)v);
  }
}
__global__ void scatter2_k(const int* __restrict__ sm, const int* __restrict__ dm,
                           int* __restrict__ cm, int* __restrict__ km,
                           const int* __restrict__ so, const int* __restrict__ dd,
                           int* __restrict__ co, int* __restrict__ ko) {
  int e = blockIdx.x * 256 + threadIdx.x;
  if (e < EM) {
    int pos = atomicAdd(&cm[dm[e]], 1);
    km[pos] = sm[e];
  } else {
    int e2 = e - EM;
    if (e2 < EO) {
      int pos = atomicAdd(&co[dd[e2]], 1);
      ko[pos] = so[e2];
    }
  }
}

// ============ fused TransformerConv: CHUNKED gathers (4 edges in flight) ============
// Padded edges use sc=-INFINITY -> exact no-op in online softmax (real edges precede
// padded ones within a chunk, so m is finite before any padded update).
__global__ void __launch_bounds__(128)
attn_fused_k(unsigned short* qh, const unsigned short* __restrict__ kk,
             const unsigned short* __restrict__ vv, const unsigned short* __restrict__ skip,
             const int* __restrict__ offs, const int* __restrict__ csr,
             const float* __restrict__ Wg, const float* __restrict__ bg,
             float* __restrict__ gateOut) {
  const int g = threadIdx.x >> 5, lane = threadIdx.x & 31;
  const int n = blockIdx.x * 4 + g;
  float4 q = b4f(*(const ushort4*)(qh + (size_t)n * ED + lane * 4));
  int lo = offs[n], hi = offs[n + 1];
  float4 O = make_float4(0.f, 0.f, 0.f, 0.f);
  float m = -INFINITY, l = 0.f;
  for (int base = lo; base < hi; base += 4) {
    int rem = hi - base;                      // >= 1
    int sidx[4];
    #pragma unroll
    for (int i = 0; i < 4; ++i) sidx[i] = (i < rem) ? csr[base + i] : 0;
    ushort4 kr[4], vr[4];
    #pragma unroll
    for (int i = 0; i < 4; ++i) {
      kr[i] = *(const ushort4*)(kk + (size_t)sidx[i] * ED + lane * 4);
      vr[i] = *(const ushort4*)(vv + (size_t)sidx[i] * ED + lane * 4);
    }
    #pragma unroll
    for (int i = 0; i < 4; ++i) {
      float4 kt = b4f(kr[i]);
      float4 vt = b4f(vr[i]);
      float p = q.x * kt.x + q.y * kt.y + q.z * kt.z + q.w * kt.w;
      p += __shfl_xor(p, 1, 64);
      p += __shfl_xor(p, 2, 64);
      float sc = (i < rem) ? p * 0.25f : -INFINITY;   // 1/sqrt(Dh); pad = no-op
      float mn = fmaxf(m, sc);
      float scale = __expf(m - mn);
      float pe = __expf(sc - mn);
      l = l * scale + pe;
      O.x = O.x * scale + pe * vt.x; O.y = O.y * scale + pe * vt.y;
      O.z = O.z * scale + pe * vt.z; O.w = O.w * scale + pe * vt.w;
      m = mn;
    }
  }
  float inv = 1.f / (l + 1e-16f);
  float4 sk = b4f(*(const ushort4*)(skip + (size_t)n * ED + lane * 4));
  float4 out = make_float4(O.x * inv + sk.x, O.y * inv + sk.y,
                           O.z * inv + sk.z, O.w * inv + sk.w);
  *(ushort4*)(qh + (size_t)n * ED + lane * 4) =
      make_ushort4(bf16_rne(out.x), bf16_rne(out.y), bf16_rne(out.z), bf16_rne(out.w));
  float4 wg = *(const float4*)(Wg + lane * 4);
  float ps = out.x * wg.x + out.y * wg.y + out.z * wg.z + out.w * wg.w;
  #pragma unroll
  for (int o = 1; o <= 16; o <<= 1) ps += __shfl_xor(ps, o, 64);
  if (lane == 0) gateOut[n] = ps + bg[0];
}

// ============ GCN gather: CHUNKED (4 edges in flight, zero-weight padding) ============
__global__ void __launch_bounds__(128)
gcn_gather_k(const float* __restrict__ x, const float* __restrict__ dinv,
             const int* __restrict__ offs, const int* __restrict__ csr,
             const float* __restrict__ bias, float* __restrict__ out,
             const float* __restrict__ Wg, const float* __restrict__ bg,
             float* __restrict__ gateOut) {
  const int g = threadIdx.x >> 5, lane = threadIdx.x & 31;
  const int n = blockIdx.x * 4 + g;
  float di = dinv[n];
  float4 xs = *(const float4*)(x + (size_t)n * ED + lane * 4);
  float w0 = di * di;
  float4 acc = make_float4(w0 * xs.x, w0 * xs.y, w0 * xs.z, w0 * xs.w);
  int lo = offs[n], hi = offs[n + 1];
  for (int base = lo; base < hi; base += 4) {
    int rem = hi - base;
    int sidx[4];
    #pragma unroll
    for (int i = 0; i < 4; ++i) sidx[i] = (i < rem) ? csr[base + i] : 0;
    float dw[4];
    #pragma unroll
    for (int i = 0; i < 4; ++i) dw[i] = (i < rem) ? di * dinv[sidx[i]] : 0.f;
    float4 vr[4];
    #pragma unroll
    for (int i = 0; i < 4; ++i)
      vr[i] = *(const float4*)(x + (size_t)sidx[i] * ED + lane * 4);
    #pragma unroll
    for (int i = 0; i < 4; ++i) {
      acc.x = fmaf(dw[i], vr[i].x, acc.x); acc.y = fmaf(dw[i], vr[i].y, acc.y);
      acc.z = fmaf(dw[i], vr[i].z, acc.z); acc.w = fmaf(dw[i], vr[i].w, acc.w);
    }
  }
  if (bias) {
    float4 b4 = *(const float4*)(bias + lane * 4);
    acc.x += b4.x; acc.y += b4.y; acc.z += b4.z; acc.w += b4.w;
  }
  *(float4*)(out + (size_t)n * ED + lane * 4) = acc;
  if (gateOut) {
    float4 wg = *(const float4*)(Wg + lane * 4);
    float ps = acc.x * wg.x + acc.y * wg.y + acc.z * wg.z + acc.w * wg.w;
    #pragma unroll
    for (int o = 1; o <= 16; o <<= 1) ps += __shfl_xor(ps, o, 64);
    if (lane == 0) gateOut[n] = ps + bg[0];
  }
}

// ============ global attention over contiguous (sorted) segments ============
static __device__ __forceinline__ int lower_bound_d(const int* a, int n, int key) {
  int lo = 0, hi = n;
  while (lo < hi) { int mid = (lo + hi) >> 1; if (a[mid] < key) lo = mid + 1; else hi = mid; }
  return lo;
}
template<bool COMBINE, bool XBF>
__global__ void __launch_bounds__(128)
gattn_k(const void* __restrict__ xv, const float* __restrict__ gate,
        const int* __restrict__ seg, int Ntot,
        const float* __restrict__ other, float* __restrict__ out) {
  const int g = threadIdx.x >> 5, lane = threadIdx.x & 31;
  const int n = blockIdx.x * 4 + g;
  __shared__ int sh[4][2];
  if (lane == 0) {
    sh[g][0] = lower_bound_d(seg, Ntot, n);
    sh[g][1] = lower_bound_d(seg, Ntot, n + 1);
  }
  __syncthreads();
  int lo = sh[g][0], hi = sh[g][1];
  float m = -INFINITY;
  for (int j = lo; j < hi; ++j) m = fmaxf(m, gate[j]);
  float ssum = 0.f;
  for (int j = lo; j < hi; ++j) ssum += __expf(gate[j] - m);
  float inv = 1.f / (ssum + 1e-16f);
  float4 acc = make_float4(0.f, 0.f, 0.f, 0.f);
  for (int j = lo; j < hi; ++j) {
    float a = __expf(gate[j] - m) * inv;
    float4 v;
    if (XBF) v = b4f(*((const ushort4*)((const unsigned short*)xv + (size_t)j * ED + lane * 4)));
    else     v = *((const float4*)((const float*)xv + (size_t)j * ED) + lane);
    acc.x = fmaf(a, v.x, acc.x); acc.y = fmaf(a, v.y, acc.y);
    acc.z = fmaf(a, v.z, acc.z); acc.w = fmaf(a, v.w, acc.w);
  }
  if (COMBINE) {
    float4 o4 = *(const float4*)(other + (size_t)n * ED + lane * 4);
    acc.x = (acc.x + o4.x) * 0.5f; acc.y = (acc.y + o4.y) * 0.5f;
    acc.z = (acc.z + o4.z) * 0.5f; acc.w = (acc.w + o4.w) * 0.5f;
  }
  *(float4*)(out + (size_t)n * ED + lane * 4) = acc;
}

// ============ final global attention NO->BB with cosine fused ====
__global__ void __launch_bounds__(128)
gattn_cos_k(const float* __restrict__ x, const float* __restrict__ gate,
            const int* __restrict__ seg, int Ntot,
            const float* __restrict__ hn, float* __restrict__ outp) {
  const int g = threadIdx.x >> 5, lane = threadIdx.x & 31;
  const int n = blockIdx.x * 4 + g;
  __shared__ int sh[4][2];
  if (lane == 0) {
    sh[g][0] = lower_bound_d(seg, Ntot, n);
    sh[g][1] = lower_bound_d(seg, Ntot, n + 1);
  }
  __syncthreads();
  int lo = sh[g][0], hi = sh[g][1];
  float m = -INFINITY;
  for (int j = lo; j < hi; ++j) m = fmaxf(m, gate[j]);
  float ssum = 0.f;
  for (int j = lo; j < hi; ++j) ssum += __expf(gate[j] - m);
  float inv = 1.f / (ssum + 1e-16f);
  float4 acc = make_float4(0.f, 0.f, 0.f, 0.f);
  for (int j = lo; j < hi; ++j) {
    float a = __expf(gate[j] - m) * inv;
    float4 v = *((const float4*)(x + (size_t)j * ED) + lane);
    acc.x = fmaf(a, v.x, acc.x); acc.y = fmaf(a, v.y, acc.y);
    acc.z = fmaf(a, v.z, acc.z); acc.w = fmaf(a, v.w, acc.w);
  }
  float4 hv = *(const float4*)(hn + (size_t)n * ED + lane * 4);
  float dot = acc.x * hv.x + acc.y * hv.y + acc.z * hv.z + acc.w * hv.w;
  float na  = acc.x * acc.x + acc.y * acc.y + acc.z * acc.z + acc.w * acc.w;
  float nb  = hv.x * hv.x + hv.y * hv.y + hv.z * hv.z + hv.w * hv.w;
  #pragma unroll
  for (int o = 1; o <= 16; o <<= 1) {
    dot += __shfl_xor(dot, o, 64);
    na  += __shfl_xor(na,  o, 64);
    nb  += __shfl_xor(nb,  o, 64);
  }
  if (lane == 0)
    outp[n] = dot / (fmaxf(sqrtf(na), 1e-8f) * fmaxf(sqrtf(nb), 1e-8f));
}

// ---- workspace layout (4-byte element offsets) ----
constexpr size_t OFF_HN    = 0;                                  // BB*ED
constexpr size_t OFF_STMT  = OFF_HN    + (size_t)BB * ED;        // NO*ED
constexpr size_t OFF_A     = OFF_STMT  + (size_t)NO * ED;        // NM*ED (miniE bf16 -> recycled)
constexpr size_t OFF_QHID  = OFF_A     + (size_t)NM * ED;        // NM*ED floats (bf16 q->hid in 1st half)
constexpr size_t OFF_CT    = OFF_QHID  + (size_t)NM * ED / 2;    // 2nd half of QHID: bf16 tables
constexpr size_t OFF_K     = OFF_QHID  + (size_t)NM * ED;        // NM*ED floats (bf16 k + bf16 skip)
constexpr size_t OFF_V     = OFF_K     + (size_t)NM * ED;        // NM*ED floats (bf16 v in 1st half)
constexpr size_t T0        = OFF_V     + (size_t)NM * ED;
constexpr size_t OFF_GATE  = T0;                                 // NM
constexpr size_t OFF_GATE2 = OFF_GATE  + (size_t)NM;             // NO
constexpr size_t OFF_DINV  = OFF_GATE2 + (size_t)NO;             // NO
constexpr size_t OFF_HISTM = OFF_DINV  + (size_t)NO;             // NM (int)
constexpr size_t OFF_HISTO = OFF_HISTM + (size_t)NM;             // NO (adjacent -> concat scan)
constexpr size_t OFF_OFFSM = OFF_HISTO + (size_t)NO;             // NM+1
constexpr size_t OFF_CURM  = OFF_OFFSM + (size_t)NM + 1;         // NM
constexpr size_t OFF_CSRM  = OFF_CURM  + (size_t)NM;             // EM
constexpr size_t OFF_OFFSO = OFF_CSRM  + (size_t)EM;             // NO+1
constexpr size_t OFF_CURO  = OFF_OFFSO + (size_t)NO + 1;         // NO
constexpr size_t OFF_CSRO  = OFF_CURO  + (size_t)NO;             // EO
constexpr size_t OFF_PART  = OFF_CSRO  + (size_t)EO;             // 512 (int)
constexpr size_t OFF_WFHI  = OFF_PART  + 512;                    // 65536 floats
constexpr size_t OFF_WFLO  = OFF_WFHI  + 65536;                  // 65536 floats
constexpr size_t WO_Q  = 0, WO_K = 2048, WO_V = 4096, WO_S = 6144, WO_W2 = 8192, WO_W3 = 12288;
// region-A recycling after attn (miniE dead):
constexpr size_t OFF_MFN   = OFF_A;                              // NO*ED
constexpr size_t OFF_AGG   = OFF_MFN   + (size_t)NO * ED;        // NO*ED
constexpr size_t OFF_H     = OFF_AGG   + (size_t)NO * ED;        // NO*HIDD
constexpr size_t OFF_T     = OFF_H     + (size_t)NO * HIDD;      // NO*ED
constexpr size_t OFF_FIN   = OFF_T     + (size_t)NO * ED;        // NO*ED

extern "C" void kernel_launch(void* const* d_in, const int* in_sizes, int n_in,
                              void* d_out, int out_size, void* d_ws, size_t ws_size,
                              hipStream_t stream) {
  const int* desc_tokens = (const int*)d_in[0];
  const int* x_tokens    = (const int*)d_in[1];
  const int* mini_tokens = (const int*)d_in[2];
  const int* src         = (const int*)d_in[3];
  const int* dst         = (const int*)d_in[4];
  const int* mini_src    = (const int*)d_in[5];
  const int* mini_dst    = (const int*)d_in[6];
  const int* mini_batch  = (const int*)d_in[7];
  const int* node_batch  = (const int*)d_in[8];
  const float* desc_table  = (const float*)d_in[9];
  const float* code_table  = (const float*)d_in[10];
  const float* code_table2 = (const float*)d_in[11];
  const float* Wq = (const float*)d_in[12]; const float* bq = (const float*)d_in[13];
  const float* Wk = (const float*)d_in[14]; const float* bk = (const float*)d_in[15];
  const float* Wv = (const float*)d_in[16]; const float* bv = (const float*)d_in[17];
  const float* Wskip = (const float*)d_in[18]; const float* bskip = (const float*)d_in[19];
  const float* W2 = (const float*)d_in[20]; const float* b2 = (const float*)d_in[21];
  const float* W3 = (const float*)d_in[22]; const float* b3 = (const float*)d_in[23];
  const float* Wg = (const float*)d_in[24]; const float* bg = (const float*)d_in[25];

  float* ws = (float*)d_ws;
  float* h_n   = ws + OFF_HN;
  float* stmt  = ws + OFF_STMT;
  unsigned short* miniE_b = (unsigned short*)(ws + OFF_A);    // bf16 [NM][128]
  unsigned short* qhid_b = (unsigned short*)(ws + OFF_QHID);  // q -> hid, bf16
  unsigned short* ctab_b  = (unsigned short*)(ws + OFF_CT);             // bf16 code_table
  unsigned short* ctab2_b = (unsigned short*)(ws + OFF_CT + (size_t)VV * ED / 2);
  unsigned short* kbuf_b = (unsigned short*)(ws + OFF_K);     // k, bf16
  unsigned short* skip_b = kbuf_b + (size_t)NM * ED;          // skip, bf16 (2nd half)
  unsigned short* vbuf_b = (unsigned short*)(ws + OFF_V);     // v, bf16
  float* gate  = ws + OFF_GATE;
  float* gate2 = ws + OFF_GATE2;
  float* dinv  = ws + OFF_DINV;
  int* histm = (int*)(ws + OFF_HISTM);
  int* histo = (int*)(ws + OFF_HISTO);
  int* offsm = (int*)(ws + OFF_OFFSM);
  int* curm  = (int*)(ws + OFF_CURM);
  int* csrm  = (int*)(ws + OFF_CSRM);
  int* offso = (int*)(ws + OFF_OFFSO);
  int* curo  = (int*)(ws + OFF_CURO);
  int* csro  = (int*)(ws + OFF_CSRO);
  int* part  = (int*)(ws + OFF_PART);
  short8* wfhi = (short8*)(ws + OFF_WFHI);
  short8* wflo = (short8*)(ws + OFF_WFLO);
  float* mini_fn = ws + OFF_MFN;
  float* aggb    = ws + OFF_AGG;
  float* hbuf    = ws + OFF_H;
  float* tbuf    = ws + OFF_T;
  float* finalS  = ws + OFF_FIN;
  float* outp    = (float*)d_out;

  // ---- all conversions in ONE launch: 6 weights + 2 tables ----
  WC6 wc;
  wc.w[0] = {Wq,    ED,   ED,   wfhi + WO_Q,  wflo + WO_Q,  (int)WO_Q};
  wc.w[1] = {Wk,    ED,   ED,   wfhi + WO_K,  wflo + WO_K,  (int)WO_K};
  wc.w[2] = {Wv,    ED,   ED,   wfhi + WO_V,  wflo + WO_V,  (int)WO_V};
  wc.w[3] = {Wskip, ED,   ED,   wfhi + WO_S,  wflo + WO_S,  (int)WO_S};
  wc.w[4] = {W2,    ED,   HIDD, wfhi + WO_W2, wflo + WO_W2, (int)WO_W2};
  wc.w[5] = {W3,    HIDD, ED,   wfhi + WO_W3, wflo + WO_W3, (int)WO_W3};
  conv_all_k<<<64 + nblk(2 * VV * ED / 4, 256), 256, 0, stream>>>(
      wc, code_table, ctab_b, code_table2, ctab2_b);

  // ---- CSR build: merged hist/scatter + single concat scan chain + fused dinv ----
  hipMemsetAsync(histm, 0, (size_t)(NM + NO) * 4, stream);
  hist2_k<<<nblk(EM + EO, 256), 256, 0, stream>>>(mini_dst, histm, dst, histo);
  chunk_sum_k<<<(NM + NO) / 256, 256, 0, stream>>>(histm, part, NM + NO);
  scan_partials2_k<<<2, 512, 0, stream>>>(part);
  scan_final2_k<<<(NM + NO) / 256, 256, 0, stream>>>(histm, part, offsm, curm,
                                                     offso, curo, dinv);
  scatter2_k<<<nblk(EM + EO, 256), 256, 0, stream>>>(mini_src, mini_dst, curm, csrm,
                                                     src, dst, curo, csro);

  // ---- all three embeddings in one launch ----
  embed_all_k<<<BB / 8 + NO / 8 + NM / 8, 256, 0, stream>>>(
      desc_tokens, desc_table, h_n, x_tokens, ctab2_b, stmt,
      mini_tokens, ctab_b, miniE_b);

  // ---- Q,K,V,Skip projections: single-term bf16 MFMA, 8 waves/block ----
  QDesc4 g4;
  g4.d[0] = {wfhi + WO_Q, bq,    qhid_b};
  g4.d[1] = {wfhi + WO_K, bk,    kbuf_b};
  g4.d[2] = {wfhi + WO_V, bv,    vbuf_b};
  g4.d[3] = {wfhi + WO_S, bskip, skip_b};
  { dim3 g(4, NM / 128); mgemm_qkvs6_k<<<g, 512, 0, stream>>>(miniE_b, g4); }

  // ---- fused transformer conv (chunked gathers) + gate ----
  attn_fused_k<<<NM / 4, 128, 0, stream>>>(qhid_b, kbuf_b, vbuf_b, skip_b,
                                           offsm, csrm, Wg, bg, gate);

  // ---- global attention mini -> NO, fused with (x + stmt)*0.5 ----
  gattn_k<true, true><<<NO / 4, 128, 0, stream>>>(qhid_b, gate, mini_batch, NM, stmt, mini_fn);

  // ---- GCN conv 1: agg = A_hat * mini_fn ; h = relu(agg @ W2 + b2) ----
  gcn_gather_k<<<NO / 4, 128, 0, stream>>>(mini_fn, dinv, offso, csro, nullptr, aggb,
                                           nullptr, nullptr, nullptr);
  { dim3 g(HIDD / 128, NO / 128);
    mgemm_k<true><<<g, 256, 0, stream>>>(aggb, wfhi + WO_W2, wflo + WO_W2, b2, hbuf, ED, HIDD); }

  // ---- GCN conv 2: t = h @ W3 ; final = A_hat * t + b3 (+ fused gate2) ----
  { dim3 g(1, NO / 128);
    mgemm_k<false><<<g, 256, 0, stream>>>(hbuf, wfhi + WO_W3, wflo + WO_W3, nullptr, tbuf, HIDD, ED); }
  gcn_gather_k<<<NO / 4, 128, 0, stream>>>(tbuf, dinv, offso, csro, b3, finalS, Wg, bg, gate2);

  // ---- global attention NO -> BB with fused cosine -> d_out [BB] ----
  gattn_cos_k<<<BB / 4, 128, 0, stream>>>(finalS, gate2, node_batch, NO, h_n, outp);
}

// Round 13
// 350.565 us; speedup vs baseline: 1.1028x; 1.0472x over previous
//
#include <hip/hip_runtime.h>
#include <hip/hip_bf16.h>
#include <math.h>

// Problem dims (fixed by reference)
#define BB   256      // batch
#define LDE  64       // desc tokens len
#define NO   10240    // outer nodes
#define LO   32       // x tokens len
#define NM   81920    // mini nodes
#define LM   16       // mini tokens len
#define EO   81920    // outer edges
#define EM   327680   // mini edges
#define ED   128      // embed dim E
#define HIDD 256      // hidden
#define NH   8        // heads
#define DH   16       // head dim
#define VV   10000    // vocab

static inline int nblk(long long n, int b) { return (int)((n + b - 1) / b); }

typedef __attribute__((ext_vector_type(8))) short short8;
typedef __attribute__((ext_vector_type(4))) float f32x4;

// ---- fp32 <-> bf16 (RNE) helpers ----
static __device__ __forceinline__ unsigned short bf16_rne(float f) {
  unsigned u = __float_as_uint(f);
  return (unsigned short)((u + 0x7fffu + ((u >> 16) & 1u)) >> 16);
}
static __device__ __forceinline__ float bf16_to_f(unsigned short h) {
  return __uint_as_float(((unsigned)h) << 16);
}
static __device__ __forceinline__ float4 b4f(ushort4 h) {
  return make_float4(bf16_to_f(h.x), bf16_to_f(h.y), bf16_to_f(h.z), bf16_to_f(h.w));
}
static __device__ __forceinline__ ushort4 f4b(float4 v) {
  return make_ushort4(bf16_rne(v.x), bf16_rne(v.y), bf16_rne(v.z), bf16_rne(v.w));
}

// ============ merged conversion kernel: 6 weights -> split-bf16 frags, 2 tables -> bf16
struct WC { const float* W; int K, M; short8* hi; short8* lo; int base; };
struct WC6 { WC w[6]; };
__global__ void __launch_bounds__(256)
conv_all_k(WC6 wc, const float* __restrict__ t1, unsigned short* __restrict__ o1,
           const float* __restrict__ t2, unsigned short* __restrict__ o2) {
  if (blockIdx.x < 64) {
    int g = blockIdx.x * 256 + threadIdx.x;   // octet id, 0..16383
    int wi = 0;
    #pragma unroll
    for (int i = 1; i < 6; ++i) if (g >= wc.w[i].base) wi = i;
    const WC c = wc.w[wi];
    int idx = g - c.base;
    int lane = idx & 63;
    int nt = (idx >> 6) % (c.M / 16);
    int kb = (idx >> 6) / (c.M / 16);
    int n = nt * 16 + (lane & 15);
    int k0 = kb * 32 + ((lane >> 4) << 3);
    short8 h, l;
    #pragma unroll
    for (int j = 0; j < 8; ++j) {
      float v = c.W[(size_t)(k0 + j) * c.M + n];
      unsigned short hb = bf16_rne(v);
      h[j] = (short)hb;
      l[j] = (short)bf16_rne(v - bf16_to_f(hb));
    }
    c.hi[idx] = h; c.lo[idx] = l;
  } else {
    int q = (blockIdx.x - 64) * 256 + threadIdx.x;   // quad id
    const int NT = VV * ED / 4;                       // 320000 per table
    if (q < NT) {
      float4 v = *(const float4*)(t1 + (size_t)q * 4);
      *(ushort4*)(o1 + (size_t)q * 4) = f4b(v);
    } else if (q < 2 * NT) {
      int q2 = q - NT;
      float4 v = *(const float4*)(t2 + (size_t)q2 * 4);
      *(ushort4*)(o2 + (size_t)q2 * 4) = f4b(v);
    }
  }
}

// ---- embedding masked mean body: 256 thr = 8 rows x 32 4-elem lanes ----
template<int L, bool TBF, bool OUTBF>
static __device__ __forceinline__ void embed_body(const int* __restrict__ tokens,
                                                  const void* __restrict__ table,
                                                  void* __restrict__ out, int blk) {
  const int r = threadIdx.x >> 5, lane = threadIdx.x & 31;
  const int n0 = blk * 8;
  __shared__ int toks[8][L];
  for (int i = threadIdx.x; i < 8 * L; i += 256)
    toks[i / L][i % L] = tokens[(size_t)n0 * L + i];
  __syncthreads();
  float4 acc = make_float4(0.f, 0.f, 0.f, 0.f);
  int cnt = 0;
  #pragma unroll
  for (int l = 0; l < L; ++l) {
    int t = toks[r][l];
    float4 v;
    if (TBF) v = b4f(*((const ushort4*)((const unsigned short*)table + (size_t)t * ED + lane * 4)));
    else     v = *(const float4*)((const float*)table + (size_t)t * ED + lane * 4);
    float msk = (t != 0) ? 1.f : 0.f;
    cnt += (t != 0);
    acc.x = fmaf(msk, v.x, acc.x); acc.y = fmaf(msk, v.y, acc.y);
    acc.z = fmaf(msk, v.z, acc.z); acc.w = fmaf(msk, v.w, acc.w);
  }
  float inv = 1.f / (float)(cnt > 0 ? cnt : 1);
  acc.x *= inv; acc.y *= inv; acc.z *= inv; acc.w *= inv;
  if (OUTBF)
    *(ushort4*)((unsigned short*)out + (size_t)(n0 + r) * ED + lane * 4) = f4b(acc);
  else
    *(float4*)((float*)out + (size_t)(n0 + r) * ED + lane * 4) = acc;
}

// all three embeddings in one launch: [0,32) desc | [32,1312) x | [1312,11552) mini
__global__ void __launch_bounds__(256)
embed_all_k(const int* __restrict__ desc_tokens, const float* __restrict__ desc_table,
            float* __restrict__ h_n,
            const int* __restrict__ x_tokens, const unsigned short* __restrict__ ctab2,
            unsigned short* __restrict__ stmt,
            const int* __restrict__ mini_tokens, const unsigned short* __restrict__ ctab,
            unsigned short* __restrict__ miniE) {
  int b = blockIdx.x;
  if (b < BB / 8) embed_body<LDE, false, false>(desc_tokens, desc_table, h_n, b);
  else if (b < BB / 8 + NO / 8) embed_body<LO, true, true>(x_tokens, ctab2, stmt, b - BB / 8);
  else embed_body<LM, true, true>(mini_tokens, ctab, miniE, b - BB / 8 - NO / 8);
}

// ========== QKVS GEMM v7: v6 + XCD-aware swizzle (same-row matrix-variants share XCD) ==
struct QDesc { const short8* bh; const float* bias; unsigned short* C; };
struct QDesc4 { QDesc d[4]; };

__global__ void __launch_bounds__(512)
mgemm_qkvs7_k(const unsigned short* __restrict__ Ab, QDesc4 g4) {
  // blocks with IDs equal mod 8 land on the same XCD (round-robin dispatch):
  // give the 4 matrix-variants of one row-block IDs differing by 8.
  const int id = blockIdx.x;
  const int mat = (id >> 3) & 3;
  const int rowb = (id & 7) | ((id >> 5) << 3);
  const QDesc d = g4.d[mat];
  const int n0 = rowb * 128;
  const int tid = threadIdx.x;
  const int w = tid >> 6, lane = tid & 63;
  const int wm = (w & 3) * 2;        // m-tile base
  const int wn = (w >> 2) * 4;       // n-tile base
  const int r = lane & 15, qd = lane >> 4;
  f32x4 acc[2][4];
  #pragma unroll
  for (int i = 0; i < 2; ++i)
    #pragma unroll
    for (int j = 0; j < 4; ++j) acc[i][j] = (f32x4){0.f, 0.f, 0.f, 0.f};
  #pragma unroll
  for (int kb = 0; kb < 4; ++kb) {
    short8 bh[4];
    #pragma unroll
    for (int j = 0; j < 4; ++j)
      bh[j] = d.bh[((size_t)kb * 8 + wn + j) * 64 + lane];
    short8 a[2];
    #pragma unroll
    for (int i = 0; i < 2; ++i)
      a[i] = *(const short8*)(Ab + (size_t)(n0 + (wm + i) * 16 + r) * ED + kb * 32 + qd * 8);
    #pragma unroll
    for (int i = 0; i < 2; ++i)
      #pragma unroll
      for (int j = 0; j < 4; ++j)
        acc[i][j] = __builtin_amdgcn_mfma_f32_16x16x32_bf16(a[i], bh[j], acc[i][j], 0, 0, 0);
  }
  #pragma unroll
  for (int i = 0; i < 2; ++i)
    #pragma unroll
    for (int j = 0; j < 4; ++j) {
      int col = (wn + j) * 16 + r;
      float bv = d.bias[col];
      #pragma unroll
      for (int rr = 0; rr < 4; ++rr) {
        int row = (wm + i) * 16 + qd * 4 + rr;
        d.C[(size_t)(n0 + row) * ED + col] = bf16_rne(acc[i][j][rr] + bv);
      }
    }
}

// ========== generic single-term bf16 GEMM: bf16 A (row-major) x frag-W -> bf16 C ======
template<bool RELU>
__global__ void __launch_bounds__(512)
mgemm_b_k(const unsigned short* __restrict__ Ab, const short8* __restrict__ Bh,
          const float* __restrict__ bias, unsigned short* __restrict__ C,
          int K, int M) {
  const int bn0 = blockIdx.x * 128;
  const int n0 = blockIdx.y * 128;
  const int tid = threadIdx.x;
  const int w = tid >> 6, lane = tid & 63;
  const int wm = (w & 3) * 2, wn = (w >> 2) * 4;
  const int r = lane & 15, qd = lane >> 4;
  const int NTm = M / 16;
  f32x4 acc[2][4];
  #pragma unroll
  for (int i = 0; i < 2; ++i)
    #pragma unroll
    for (int j = 0; j < 4; ++j) acc[i][j] = (f32x4){0.f, 0.f, 0.f, 0.f};
  const int kbn = K / 32;
  for (int kb = 0; kb < kbn; ++kb) {
    short8 bh[4];
    #pragma unroll
    for (int j = 0; j < 4; ++j)
      bh[j] = Bh[((size_t)kb * NTm + (bn0 >> 4) + wn + j) * 64 + lane];
    short8 a[2];
    #pragma unroll
    for (int i = 0; i < 2; ++i)
      a[i] = *(const short8*)(Ab + (size_t)(n0 + (wm + i) * 16 + r) * K + kb * 32 + qd * 8);
    #pragma unroll
    for (int i = 0; i < 2; ++i)
      #pragma unroll
      for (int j = 0; j < 4; ++j)
        acc[i][j] = __builtin_amdgcn_mfma_f32_16x16x32_bf16(a[i], bh[j], acc[i][j], 0, 0, 0);
  }
  #pragma unroll
  for (int i = 0; i < 2; ++i)
    #pragma unroll
    for (int j = 0; j < 4; ++j) {
      int col = bn0 + (wn + j) * 16 + r;
      float bv = bias ? bias[col] : 0.f;
      #pragma unroll
      for (int rr = 0; rr < 4; ++rr) {
        int row = n0 + (wm + i) * 16 + qd * 4 + rr;
        float v = acc[i][j][rr] + bv;
        if (RELU) v = fmaxf(v, 0.f);
        C[(size_t)row * M + col] = bf16_rne(v);
      }
    }
}

// ================= CSR build (merged scan chain) =================
__global__ void hist2_k(const int* __restrict__ dm, int* __restrict__ hm,
                        const int* __restrict__ dd, int* __restrict__ ho) {
  int e = blockIdx.x * 256 + threadIdx.x;
  if (e < EM) atomicAdd(&hm[dm[e]], 1);
  else { int e2 = e - EM; if (e2 < EO) atomicAdd(&ho[dd[e2]], 1); }
}
__global__ void chunk_sum_k(const int* __restrict__ hist, int* __restrict__ partials, int N) {
  __shared__ int sd[256];
  int i = blockIdx.x * 256 + threadIdx.x;
  sd[threadIdx.x] = (i < N) ? hist[i] : 0;
  __syncthreads();
  for (int s = 128; s > 0; s >>= 1) {
    if (threadIdx.x < s) sd[threadIdx.x] += sd[threadIdx.x + s];
    __syncthreads();
  }
  if (threadIdx.x == 0) partials[blockIdx.x] = sd[0];
}
__global__ void scan_partials2_k(int* __restrict__ p) {
  __shared__ int sd[512];
  int base = (blockIdx.x == 0) ? 0 : NM / 256;
  int B    = (blockIdx.x == 0) ? NM / 256 : NO / 256;
  int t = threadIdx.x;
  int v = (t < B) ? p[base + t] : 0;
  sd[t] = v; __syncthreads();
  for (int off = 1; off < 512; off <<= 1) {
    int a = (t >= off) ? sd[t - off] : 0;
    __syncthreads();
    sd[t] += a;
    __syncthreads();
  }
  if (t < B) p[base + t] = sd[t] - v;   // exclusive
}
__global__ void scan_final2_k(const int* __restrict__ hist, const int* __restrict__ partials,
                              int* __restrict__ offsm, int* __restrict__ curm,
                              int* __restrict__ offso, int* __restrict__ curo,
                              float* __restrict__ dinv) {
  __shared__ int sd[256];
  int i = blockIdx.x * 256 + threadIdx.x;
  int v = hist[i];
  sd[threadIdx.x] = v; __syncthreads();
  for (int off = 1; off < 256; off <<= 1) {
    int a = (threadIdx.x >= off) ? sd[threadIdx.x - off] : 0;
    __syncthreads();
    sd[threadIdx.x] += a;
    __syncthreads();
  }
  int excl = sd[threadIdx.x] - v + partials[blockIdx.x];
  if (i < NM) {
    offsm[i] = excl; curm[i] = excl;
    if (i == NM - 1) offsm[NM] = excl + v;
  } else {
    int i2 = i - NM;
    offso[i2] = excl; curo[i2] = excl;
    if (i2 == NO - 1) offso[NO] = excl + v;
    dinv[i2] = 1.f / sqrtf(1.f + (float)v);
  }
}
__global__ void scatter2_k(const int* __restrict__ sm, const int* __restrict__ dm,
                           int* __restrict__ cm, int* __restrict__ km,
                           const int* __restrict__ so, const int* __restrict__ dd,
                           int* __restrict__ co, int* __restrict__ ko) {
  int e = blockIdx.x * 256 + threadIdx.x;
  if (e < EM) {
    int pos = atomicAdd(&cm[dm[e]], 1);
    km[pos] = sm[e];
  } else {
    int e2 = e - EM;
    if (e2 < EO) {
      int pos = atomicAdd(&co[dd[e2]], 1);
      ko[pos] = so[e2];
    }
  }
}

// ============ fused TransformerConv: CHUNKED gathers (4 edges in flight) ============
__global__ void __launch_bounds__(128)
attn_fused_k(unsigned short* qh, const unsigned short* __restrict__ kk,
             const unsigned short* __restrict__ vv, const unsigned short* __restrict__ skip,
             const int* __restrict__ offs, const int* __restrict__ csr,
             const float* __restrict__ Wg, const float* __restrict__ bg,
             float* __restrict__ gateOut) {
  const int g = threadIdx.x >> 5, lane = threadIdx.x & 31;
  const int n = blockIdx.x * 4 + g;
  float4 q = b4f(*(const ushort4*)(qh + (size_t)n * ED + lane * 4));
  int lo = offs[n], hi = offs[n + 1];
  float4 O = make_float4(0.f, 0.f, 0.f, 0.f);
  float m = -INFINITY, l = 0.f;
  for (int base = lo; base < hi; base += 4) {
    int rem = hi - base;                      // >= 1
    int sidx[4];
    #pragma unroll
    for (int i = 0; i < 4; ++i) sidx[i] = (i < rem) ? csr[base + i] : 0;
    ushort4 kr[4], vr[4];
    #pragma unroll
    for (int i = 0; i < 4; ++i) {
      kr[i] = *(const ushort4*)(kk + (size_t)sidx[i] * ED + lane * 4);
      vr[i] = *(const ushort4*)(vv + (size_t)sidx[i] * ED + lane * 4);
    }
    #pragma unroll
    for (int i = 0; i < 4; ++i) {
      float4 kt = b4f(kr[i]);
      float4 vt = b4f(vr[i]);
      float p = q.x * kt.x + q.y * kt.y + q.z * kt.z + q.w * kt.w;
      p += __shfl_xor(p, 1, 64);
      p += __shfl_xor(p, 2, 64);
      float sc = (i < rem) ? p * 0.25f : -INFINITY;   // 1/sqrt(Dh); pad = no-op
      float mn = fmaxf(m, sc);
      float scale = __expf(m - mn);
      float pe = __expf(sc - mn);
      l = l * scale + pe;
      O.x = O.x * scale + pe * vt.x; O.y = O.y * scale + pe * vt.y;
      O.z = O.z * scale + pe * vt.z; O.w = O.w * scale + pe * vt.w;
      m = mn;
    }
  }
  float inv = 1.f / (l + 1e-16f);
  float4 sk = b4f(*(const ushort4*)(skip + (size_t)n * ED + lane * 4));
  float4 out = make_float4(O.x * inv + sk.x, O.y * inv + sk.y,
                           O.z * inv + sk.z, O.w * inv + sk.w);
  *(ushort4*)(qh + (size_t)n * ED + lane * 4) = f4b(out);
  float4 wg = *(const float4*)(Wg + lane * 4);
  float ps = out.x * wg.x + out.y * wg.y + out.z * wg.z + out.w * wg.w;
  #pragma unroll
  for (int o = 1; o <= 16; o <<= 1) ps += __shfl_xor(ps, o, 64);
  if (lane == 0) gateOut[n] = ps + bg[0];
}

// ============ GCN gather (bf16 in/out): CHUNKED (4 edges in flight) ============
__global__ void __launch_bounds__(128)
gcn_gather_b_k(const unsigned short* __restrict__ x, const float* __restrict__ dinv,
               const int* __restrict__ offs, const int* __restrict__ csr,
               const float* __restrict__ bias, unsigned short* __restrict__ out,
               const float* __restrict__ Wg, const float* __restrict__ bg,
               float* __restrict__ gateOut) {
  const int g = threadIdx.x >> 5, lane = threadIdx.x & 31;
  const int n = blockIdx.x * 4 + g;
  float di = dinv[n];
  float4 xs = b4f(*(const ushort4*)(x + (size_t)n * ED + lane * 4));
  float w0 = di * di;
  float4 acc = make_float4(w0 * xs.x, w0 * xs.y, w0 * xs.z, w0 * xs.w);
  int lo = offs[n], hi = offs[n + 1];
  for (int base = lo; base < hi; base += 4) {
    int rem = hi - base;
    int sidx[4];
    #pragma unroll
    for (int i = 0; i < 4; ++i) sidx[i] = (i < rem) ? csr[base + i] : 0;
    float dw[4];
    #pragma unroll
    for (int i = 0; i < 4; ++i) dw[i] = (i < rem) ? di * dinv[sidx[i]] : 0.f;
    ushort4 vr[4];
    #pragma unroll
    for (int i = 0; i < 4; ++i)
      vr[i] = *(const ushort4*)(x + (size_t)sidx[i] * ED + lane * 4);
    #pragma unroll
    for (int i = 0; i < 4; ++i) {
      float4 v = b4f(vr[i]);
      acc.x = fmaf(dw[i], v.x, acc.x); acc.y = fmaf(dw[i], v.y, acc.y);
      acc.z = fmaf(dw[i], v.z, acc.z); acc.w = fmaf(dw[i], v.w, acc.w);
    }
  }
  if (bias) {
    float4 b4 = *(const float4*)(bias + lane * 4);
    acc.x += b4.x; acc.y += b4.y; acc.z += b4.z; acc.w += b4.w;
  }
  *(ushort4*)(out + (size_t)n * ED + lane * 4) = f4b(acc);
  if (gateOut) {
    float4 wg = *(const float4*)(Wg + lane * 4);
    float ps = acc.x * wg.x + acc.y * wg.y + acc.z * wg.z + acc.w * wg.w;
    #pragma unroll
    for (int o = 1; o <= 16; o <<= 1) ps += __shfl_xor(ps, o, 64);
    if (lane == 0) gateOut[n] = ps + bg[0];
  }
}

// ============ global attention mini->NO (bf16 x/other/out) + combine ============
static __device__ __forceinline__ int lower_bound_d(const int* a, int n, int key) {
  int lo = 0, hi = n;
  while (lo < hi) { int mid = (lo + hi) >> 1; if (a[mid] < key) lo = mid + 1; else hi = mid; }
  return lo;
}
__global__ void __launch_bounds__(128)
gattn_comb_b_k(const unsigned short* __restrict__ xv, const float* __restrict__ gate,
               const int* __restrict__ seg, int Ntot,
               const unsigned short* __restrict__ other, unsigned short* __restrict__ out) {
  const int g = threadIdx.x >> 5, lane = threadIdx.x & 31;
  const int n = blockIdx.x * 4 + g;
  __shared__ int sh[4][2];
  if (lane == 0) {
    sh[g][0] = lower_bound_d(seg, Ntot, n);
    sh[g][1] = lower_bound_d(seg, Ntot, n + 1);
  }
  __syncthreads();
  int lo = sh[g][0], hi = sh[g][1];
  float m = -INFINITY;
  for (int j = lo; j < hi; ++j) m = fmaxf(m, gate[j]);
  float ssum = 0.f;
  for (int j = lo; j < hi; ++j) ssum += __expf(gate[j] - m);
  float inv = 1.f / (ssum + 1e-16f);
  float4 acc = make_float4(0.f, 0.f, 0.f, 0.f);
  for (int j = lo; j < hi; ++j) {
    float a = __expf(gate[j] - m) * inv;
    float4 v = b4f(*(const ushort4*)(xv + (size_t)j * ED + lane * 4));
    acc.x = fmaf(a, v.x, acc.x); acc.y = fmaf(a, v.y, acc.y);
    acc.z = fmaf(a, v.z, acc.z); acc.w = fmaf(a, v.w, acc.w);
  }
  float4 o4 = b4f(*(const ushort4*)(other + (size_t)n * ED + lane * 4));
  acc.x = (acc.x + o4.x) * 0.5f; acc.y = (acc.y + o4.y) * 0.5f;
  acc.z = (acc.z + o4.z) * 0.5f; acc.w = (acc.w + o4.w) * 0.5f;
  *(ushort4*)(out + (size_t)n * ED + lane * 4) = f4b(acc);
}

// ============ final global attention NO->BB (bf16 x) with cosine fused ====
__global__ void __launch_bounds__(128)
gattn_cos_k(const unsigned short* __restrict__ x, const float* __restrict__ gate,
            const int* __restrict__ seg, int Ntot,
            const float* __restrict__ hn, float* __restrict__ outp) {
  const int g = threadIdx.x >> 5, lane = threadIdx.x & 31;
  const int n = blockIdx.x * 4 + g;
  __shared__ int sh[4][2];
  if (lane == 0) {
    sh[g][0] = lower_bound_d(seg, Ntot, n);
    sh[g][1] = lower_bound_d(seg, Ntot, n + 1);
  }
  __syncthreads();
  int lo = sh[g][0], hi = sh[g][1];
  float m = -INFINITY;
  for (int j = lo; j < hi; ++j) m = fmaxf(m, gate[j]);
  float ssum = 0.f;
  for (int j = lo; j < hi; ++j) ssum += __expf(gate[j] - m);
  float inv = 1.f / (ssum + 1e-16f);
  float4 acc = make_float4(0.f, 0.f, 0.f, 0.f);
  for (int j = lo; j < hi; ++j) {
    float a = __expf(gate[j] - m) * inv;
    float4 v = b4f(*(const ushort4*)(x + (size_t)j * ED + lane * 4));
    acc.x = fmaf(a, v.x, acc.x); acc.y = fmaf(a, v.y, acc.y);
    acc.z = fmaf(a, v.z, acc.z); acc.w = fmaf(a, v.w, acc.w);
  }
  float4 hv = *(const float4*)(hn + (size_t)n * ED + lane * 4);
  float dot = acc.x * hv.x + acc.y * hv.y + acc.z * hv.z + acc.w * hv.w;
  float na  = acc.x * acc.x + acc.y * acc.y + acc.z * acc.z + acc.w * acc.w;
  float nb  = hv.x * hv.x + hv.y * hv.y + hv.z * hv.z + hv.w * hv.w;
  #pragma unroll
  for (int o = 1; o <= 16; o <<= 1) {
    dot += __shfl_xor(dot, o, 64);
    na  += __shfl_xor(na,  o, 64);
    nb  += __shfl_xor(nb,  o, 64);
  }
  if (lane == 0)
    outp[n] = dot / (fmaxf(sqrtf(na), 1e-8f) * fmaxf(sqrtf(nb), 1e-8f));
}

// ---- workspace layout (4-byte element offsets) ----
constexpr size_t OFF_HN    = 0;                                  // BB*ED
constexpr size_t OFF_STMT  = OFF_HN    + (size_t)BB * ED;        // NO*ED (bf16 in half)
constexpr size_t OFF_A     = OFF_STMT  + (size_t)NO * ED;        // NM*ED (miniE bf16 -> recycled)
constexpr size_t OFF_QHID  = OFF_A     + (size_t)NM * ED;        // NM*ED floats (bf16 q->hid in 1st half)
constexpr size_t OFF_CT    = OFF_QHID  + (size_t)NM * ED / 2;    // 2nd half of QHID: bf16 tables
constexpr size_t OFF_K     = OFF_QHID  + (size_t)NM * ED;        // NM*ED floats (bf16 k + bf16 skip)
constexpr size_t OFF_V     = OFF_K     + (size_t)NM * ED;        // NM*ED floats (bf16 v in 1st half)
constexpr size_t T0        = OFF_V     + (size_t)NM * ED;
constexpr size_t OFF_GATE  = T0;                                 // NM
constexpr size_t OFF_GATE2 = OFF_GATE  + (size_t)NM;             // NO
constexpr size_t OFF_DINV  = OFF_GATE2 + (size_t)NO;             // NO
constexpr size_t OFF_HISTM = OFF_DINV  + (size_t)NO;             // NM (int)
constexpr size_t OFF_HISTO = OFF_HISTM + (size_t)NM;             // NO (adjacent -> concat scan)
constexpr size_t OFF_OFFSM = OFF_HISTO + (size_t)NO;             // NM+1
constexpr size_t OFF_CURM  = OFF_OFFSM + (size_t)NM + 1;         // NM
constexpr size_t OFF_CSRM  = OFF_CURM  + (size_t)NM;             // EM
constexpr size_t OFF_OFFSO = OFF_CSRM  + (size_t)EM;             // NO+1
constexpr size_t OFF_CURO  = OFF_OFFSO + (size_t)NO + 1;         // NO
constexpr size_t OFF_CSRO  = OFF_CURO  + (size_t)NO;             // EO
constexpr size_t OFF_PART  = OFF_CSRO  + (size_t)EO;             // 512 (int)
constexpr size_t OFF_WFHI  = OFF_PART  + 512;                    // 65536 floats
constexpr size_t OFF_WFLO  = OFF_WFHI  + 65536;                  // 65536 floats
constexpr size_t WO_Q  = 0, WO_K = 2048, WO_V = 4096, WO_S = 6144, WO_W2 = 8192, WO_W3 = 12288;
// region-A recycling after attn (miniE dead): all bf16 now (half of each float slot)
constexpr size_t OFF_MFN   = OFF_A;                              // NO*ED (bf16)
constexpr size_t OFF_AGG   = OFF_MFN   + (size_t)NO * ED;        // NO*ED (bf16)
constexpr size_t OFF_H     = OFF_AGG   + (size_t)NO * ED;        // NO*HIDD (bf16)
constexpr size_t OFF_T     = OFF_H     + (size_t)NO * HIDD;      // NO*ED (bf16)
constexpr size_t OFF_FIN   = OFF_T     + (size_t)NO * ED;        // NO*ED (bf16)

extern "C" void kernel_launch(void* const* d_in, const int* in_sizes, int n_in,
                              void* d_out, int out_size, void* d_ws, size_t ws_size,
                              hipStream_t stream) {
  const int* desc_tokens = (const int*)d_in[0];
  const int* x_tokens    = (const int*)d_in[1];
  const int* mini_tokens = (const int*)d_in[2];
  const int* src         = (const int*)d_in[3];
  const int* dst         = (const int*)d_in[4];
  const int* mini_src    = (const int*)d_in[5];
  const int* mini_dst    = (const int*)d_in[6];
  const int* mini_batch  = (const int*)d_in[7];
  const int* node_batch  = (const int*)d_in[8];
  const float* desc_table  = (const float*)d_in[9];
  const float* code_table  = (const float*)d_in[10];
  const float* code_table2 = (const float*)d_in[11];
  const float* Wq = (const float*)d_in[12]; const float* bq = (const float*)d_in[13];
  const float* Wk = (const float*)d_in[14]; const float* bk = (const float*)d_in[15];
  const float* Wv = (const float*)d_in[16]; const float* bv = (const float*)d_in[17];
  const float* Wskip = (const float*)d_in[18]; const float* bskip = (const float*)d_in[19];
  const float* W2 = (const float*)d_in[20]; const float* b2 = (const float*)d_in[21];
  const float* W3 = (const float*)d_in[22]; const float* b3 = (const float*)d_in[23];
  const float* Wg = (const float*)d_in[24]; const float* bg = (const float*)d_in[25];

  float* ws = (float*)d_ws;
  float* h_n   = ws + OFF_HN;
  unsigned short* stmt_b  = (unsigned short*)(ws + OFF_STMT);
  unsigned short* miniE_b = (unsigned short*)(ws + OFF_A);    // bf16 [NM][128]
  unsigned short* qhid_b = (unsigned short*)(ws + OFF_QHID);  // q -> hid, bf16
  unsigned short* ctab_b  = (unsigned short*)(ws + OFF_CT);
  unsigned short* ctab2_b = (unsigned short*)(ws + OFF_CT + (size_t)VV * ED / 2);
  unsigned short* kbuf_b = (unsigned short*)(ws + OFF_K);     // k, bf16
  unsigned short* skip_b = kbuf_b + (size_t)NM * ED;          // skip, bf16 (2nd half)
  unsigned short* vbuf_b = (unsigned short*)(ws + OFF_V);     // v, bf16
  float* gate  = ws + OFF_GATE;
  float* gate2 = ws + OFF_GATE2;
  float* dinv  = ws + OFF_DINV;
  int* histm = (int*)(ws + OFF_HISTM);
  int* histo = (int*)(ws + OFF_HISTO);
  int* offsm = (int*)(ws + OFF_OFFSM);
  int* curm  = (int*)(ws + OFF_CURM);
  int* csrm  = (int*)(ws + OFF_CSRM);
  int* offso = (int*)(ws + OFF_OFFSO);
  int* curo  = (int*)(ws + OFF_CURO);
  int* csro  = (int*)(ws + OFF_CSRO);
  int* part  = (int*)(ws + OFF_PART);
  short8* wfhi = (short8*)(ws + OFF_WFHI);
  short8* wflo = (short8*)(ws + OFF_WFLO);
  unsigned short* mini_fn_b = (unsigned short*)(ws + OFF_MFN);
  unsigned short* aggb_b    = (unsigned short*)(ws + OFF_AGG);
  unsigned short* hbuf_b    = (unsigned short*)(ws + OFF_H);
  unsigned short* tbuf_b    = (unsigned short*)(ws + OFF_T);
  unsigned short* finalS_b  = (unsigned short*)(ws + OFF_FIN);
  float* outp    = (float*)d_out;

  // ---- all conversions in ONE launch: 6 weights + 2 tables ----
  WC6 wc;
  wc.w[0] = {Wq,    ED,   ED,   wfhi + WO_Q,  wflo + WO_Q,  (int)WO_Q};
  wc.w[1] = {Wk,    ED,   ED,   wfhi + WO_K,  wflo + WO_K,  (int)WO_K};
  wc.w[2] = {Wv,    ED,   ED,   wfhi + WO_V,  wflo + WO_V,  (int)WO_V};
  wc.w[3] = {Wskip, ED,   ED,   wfhi + WO_S,  wflo + WO_S,  (int)WO_S};
  wc.w[4] = {W2,    ED,   HIDD, wfhi + WO_W2, wflo + WO_W2, (int)WO_W2};
  wc.w[5] = {W3,    HIDD, ED,   wfhi + WO_W3, wflo + WO_W3, (int)WO_W3};
  conv_all_k<<<64 + nblk(2 * VV * ED / 4, 256), 256, 0, stream>>>(
      wc, code_table, ctab_b, code_table2, ctab2_b);

  // ---- CSR build: merged hist/scatter + single concat scan chain + fused dinv ----
  hipMemsetAsync(histm, 0, (size_t)(NM + NO) * 4, stream);
  hist2_k<<<nblk(EM + EO, 256), 256, 0, stream>>>(mini_dst, histm, dst, histo);
  chunk_sum_k<<<(NM + NO) / 256, 256, 0, stream>>>(histm, part, NM + NO);
  scan_partials2_k<<<2, 512, 0, stream>>>(part);
  scan_final2_k<<<(NM + NO) / 256, 256, 0, stream>>>(histm, part, offsm, curm,
                                                     offso, curo, dinv);
  scatter2_k<<<nblk(EM + EO, 256), 256, 0, stream>>>(mini_src, mini_dst, curm, csrm,
                                                     src, dst, curo, csro);

  // ---- all three embeddings in one launch ----
  embed_all_k<<<BB / 8 + NO / 8 + NM / 8, 256, 0, stream>>>(
      desc_tokens, desc_table, h_n, x_tokens, ctab2_b, stmt_b,
      mini_tokens, ctab_b, miniE_b);

  // ---- Q,K,V,Skip projections: single-term bf16 MFMA, XCD-swizzled 1D grid ----
  QDesc4 g4;
  g4.d[0] = {wfhi + WO_Q, bq,    qhid_b};
  g4.d[1] = {wfhi + WO_K, bk,    kbuf_b};
  g4.d[2] = {wfhi + WO_V, bv,    vbuf_b};
  g4.d[3] = {wfhi + WO_S, bskip, skip_b};
  mgemm_qkvs7_k<<<4 * (NM / 128), 512, 0, stream>>>(miniE_b, g4);

  // ---- fused transformer conv (chunked gathers) + gate ----
  attn_fused_k<<<NM / 4, 128, 0, stream>>>(qhid_b, kbuf_b, vbuf_b, skip_b,
                                           offsm, csrm, Wg, bg, gate);

  // ---- global attention mini -> NO, fused with (x + stmt)*0.5 (all bf16) ----
  gattn_comb_b_k<<<NO / 4, 128, 0, stream>>>(qhid_b, gate, mini_batch, NM,
                                             stmt_b, mini_fn_b);

  // ---- GCN conv 1: agg = A_hat * mini_fn (bf16) ; h = relu(agg @ W2 + b2) (bf16) ----
  gcn_gather_b_k<<<NO / 4, 128, 0, stream>>>(mini_fn_b, dinv, offso, csro, nullptr,
                                             aggb_b, nullptr, nullptr, nullptr);
  { dim3 g(HIDD / 128, NO / 128);
    mgemm_b_k<true><<<g, 512, 0, stream>>>(aggb_b, wfhi + WO_W2, b2, hbuf_b, ED, HIDD); }

  // ---- GCN conv 2: t = h @ W3 (bf16) ; final = A_hat * t + b3 (+ gate2) ----
  { dim3 g(1, NO / 128);
    mgemm_b_k<false><<<g, 512, 0, stream>>>(hbuf_b, wfhi + WO_W3, nullptr, tbuf_b, HIDD, ED); }
  gcn_gather_b_k<<<NO / 4, 128, 0, stream>>>(tbuf_b, dinv, offso, csro, b3, finalS_b,
                                             Wg, bg, gate2);

  // ---- global attention NO -> BB with fused cosine -> d_out [BB] ----
  gattn_cos_k<<<BB / 4, 128, 0, stream>>>(finalS_b, gate2, node_batch, NO, h_n, outp);
}